// Round 2
// baseline (5696.544 us; speedup 1.0000x reference)
//
#include <hip/hip_runtime.h>
#include <math.h>

#define N_NODES 100000
#define N_EDGES 3200000
#define HDIM 128

// ---------------------------------------------------------------------------
__global__ __launch_bounds__(256) void zero_f32(float* __restrict__ p, int n) {
  int i = blockIdx.x * 256 + threadIdx.x;
  if (i < n) p[i] = 0.f;
}

// ---------------------------------------------------------------------------
// Tiled fp32 GEMM, K fixed at 128. Y[n][j] = sum_k A[n][k] * W(k,j) + bias[j]
//  BT=false: W stored [128][OUT] row-major (W[k][j])   — emb, conv, mlp, e2
//  BT=true : W stored [OUT][128] row-major (W[j][k])   — gru Wih/Whh (y = A@W^T)
//  ACC=true: Y += result (no bias read skipped; bias may be null)
// Block: 256 threads, tile 64 rows x 128 cols, thread tile 4x8.
// ---------------------------------------------------------------------------
template<bool BT, bool ACC>
__global__ __launch_bounds__(256) void gemm_k128(
    const float* __restrict__ A, const float* __restrict__ W,
    const float* __restrict__ bias, float* __restrict__ Y,
    int M, int OUT)
{
  __shared__ alignas(16) float lds_a[32 * 68];    // [kk][row], stride 68 (pad)
  __shared__ alignas(16) float lds_b[32 * 132];   // [kk][col], stride 132 (pad)
  const int tid = threadIdx.x;
  const int tx = tid & 15;          // col group (8 cols each)
  const int ty = tid >> 4;          // row group (4 rows each)
  const int rowBase = blockIdx.x * 64;
  const int colBase = blockIdx.y * 128;

  float acc[4][8];
#pragma unroll
  for (int r = 0; r < 4; r++)
#pragma unroll
    for (int c = 0; c < 8; c++) acc[r][c] = 0.f;

  for (int k0 = 0; k0 < 128; k0 += 32) {
    // ---- stage A chunk: 64 rows x 32 k (transpose to [kk][row]) ----
#pragma unroll
    for (int i = 0; i < 2; i++) {
      int idx = tid + i * 256;          // 0..511
      int r   = idx >> 3;               // 0..63
      int kk  = (idx & 7) << 2;         // 0,4,..,28
      int gr  = rowBase + r;
      float4 v = make_float4(0.f, 0.f, 0.f, 0.f);
      if (gr < M) v = *(const float4*)(A + (size_t)gr * HDIM + k0 + kk);
      lds_a[(kk + 0) * 68 + r] = v.x;
      lds_a[(kk + 1) * 68 + r] = v.y;
      lds_a[(kk + 2) * 68 + r] = v.z;
      lds_a[(kk + 3) * 68 + r] = v.w;
    }
    // ---- stage B chunk: 32 k x 128 cols ----
    if (!BT) {
#pragma unroll
      for (int i = 0; i < 4; i++) {
        int idx = tid + i * 256;        // 0..1023
        int kk  = idx >> 5;             // 0..31
        int j   = (idx & 31) << 2;      // 0..124
        int gj  = colBase + j;
        float4 v = make_float4(0.f, 0.f, 0.f, 0.f);
        if (gj < OUT) v = *(const float4*)(W + (size_t)(k0 + kk) * OUT + gj);
        *((float4*)&lds_b[kk * 132 + j]) = v;
      }
    } else {
#pragma unroll
      for (int i = 0; i < 4; i++) {
        int idx = tid + i * 256;        // 0..1023
        int j   = idx >> 3;             // 0..127
        int k4  = (idx & 7) << 2;       // 0..28
        int gj  = colBase + j;
        float4 v = make_float4(0.f, 0.f, 0.f, 0.f);
        if (gj < OUT) v = *(const float4*)(W + (size_t)gj * HDIM + k0 + k4);
        lds_b[(k4 + 0) * 132 + j] = v.x;
        lds_b[(k4 + 1) * 132 + j] = v.y;
        lds_b[(k4 + 2) * 132 + j] = v.z;
        lds_b[(k4 + 3) * 132 + j] = v.w;
      }
    }
    __syncthreads();
#pragma unroll 8
    for (int kk = 0; kk < 32; kk++) {
      float4 a4 = *(const float4*)&lds_a[kk * 68 + ty * 4];
      float4 b0 = *(const float4*)&lds_b[kk * 132 + tx * 8];
      float4 b1 = *(const float4*)&lds_b[kk * 132 + tx * 8 + 4];
      float av[4] = {a4.x, a4.y, a4.z, a4.w};
      float bv[8] = {b0.x, b0.y, b0.z, b0.w, b1.x, b1.y, b1.z, b1.w};
#pragma unroll
      for (int r = 0; r < 4; r++)
#pragma unroll
        for (int c = 0; c < 8; c++)
          acc[r][c] = fmaf(av[r], bv[c], acc[r][c]);
    }
    __syncthreads();
  }

  int col = colBase + tx * 8;
  if (col >= OUT) return;               // OUT is a multiple of 8 -> f4-granular
  float bv[8];
#pragma unroll
  for (int c = 0; c < 8; c++) bv[c] = bias ? bias[col + c] : 0.f;
#pragma unroll
  for (int r = 0; r < 4; r++) {
    int gr = rowBase + ty * 4 + r;
    if (gr >= M) continue;
    float* yp = Y + (size_t)gr * OUT + col;
    float4 o0 = make_float4(acc[r][0] + bv[0], acc[r][1] + bv[1],
                            acc[r][2] + bv[2], acc[r][3] + bv[3]);
    float4 o1 = make_float4(acc[r][4] + bv[4], acc[r][5] + bv[5],
                            acc[r][6] + bv[6], acc[r][7] + bv[7]);
    if (ACC) {
      float4 y0 = *(float4*)yp;
      float4 y1 = *(float4*)(yp + 4);
      o0.x += y0.x; o0.y += y0.y; o0.z += y0.z; o0.w += y0.w;
      o1.x += y1.x; o1.y += y1.y; o1.z += y1.z; o1.w += y1.w;
    }
    *(float4*)yp       = o0;
    *(float4*)(yp + 4) = o1;
  }
}

// ---------------------------------------------------------------------------
// Edge scatter: agg[dst] += w * m[src]. One wave (64 lanes) per edge, 2 cols/lane.
// ---------------------------------------------------------------------------
__global__ __launch_bounds__(256) void scatter_add(
    const float* __restrict__ m, const int* __restrict__ ei,
    const float* __restrict__ ew, float* __restrict__ agg)
{
  int e    = blockIdx.x * 4 + (threadIdx.x >> 6);   // grid = E/4 exactly
  int lane = threadIdx.x & 63;
  int s = ei[e];
  int d = ei[N_EDGES + e];
  float w = ew[e];
  float v0 = m[(size_t)s * HDIM + lane] * w;
  float v1 = m[(size_t)s * HDIM + 64 + lane] * w;
  atomicAdd(agg + (size_t)d * HDIM + lane, v0);
  atomicAdd(agg + (size_t)d * HDIM + 64 + lane, v1);
}

// ---------------------------------------------------------------------------
// GRU elementwise update (in place on x chunk). gi/gh are [Mc][384] (r|z|n).
// total = Mc * 128
// ---------------------------------------------------------------------------
__global__ __launch_bounds__(256) void gru_elem(
    const float* __restrict__ gi, const float* __restrict__ gh,
    float* __restrict__ x, int total)
{
  int i = blockIdx.x * 256 + threadIdx.x;
  if (i >= total) return;
  int n = i >> 7, j = i & 127;
  size_t b = (size_t)n * 384 + j;
  float ir = gi[b], iz = gi[b + 128], inn = gi[b + 256];
  float hr = gh[b], hz = gh[b + 128], hn  = gh[b + 256];
  float r  = 1.f / (1.f + __expf(-(ir + hr)));
  float z  = 1.f / (1.f + __expf(-(iz + hz)));
  float nn = tanhf(inn + r * hn);
  float xo = x[i];
  x[i] = (1.f - z) * nn + z * xo;
}

// ---------------------------------------------------------------------------
// BatchNorm: per-column sum / sumsq partials -> atomic accumulate
// ---------------------------------------------------------------------------
__global__ __launch_bounds__(256) void bn_stats(
    const float* __restrict__ x, float* __restrict__ sums)
{
  __shared__ float ls[256], lq[256];
  int tid  = threadIdx.x;
  int col  = tid & 127, half = tid >> 7;
  int r0   = blockIdx.x * 128;
  int rend = min(N_NODES, r0 + 128);
  float s = 0.f, q = 0.f;
  for (int r = r0 + half; r < rend; r += 2) {
    float v = x[(size_t)r * HDIM + col];
    s += v; q += v * v;
  }
  ls[tid] = s; lq[tid] = q;
  __syncthreads();
  if (tid < 128) {
    atomicAdd(&sums[col],       ls[tid] + ls[tid + 128]);
    atomicAdd(&sums[128 + col], lq[tid] + lq[tid + 128]);
  }
}

__global__ void bn_finalize(float* __restrict__ sums,
                            const float* __restrict__ gamma,
                            const float* __restrict__ beta)
{
  int j = threadIdx.x;           // 128 threads
  float mean = sums[j] / (float)N_NODES;
  float var  = sums[128 + j] / (float)N_NODES - mean * mean;
  float inv  = rsqrtf(var + 1e-5f);
  sums[256 + j] = gamma[j] * inv;                    // scale
  sums[384 + j] = beta[j] - mean * gamma[j] * inv;   // shift
}

// x = x*scale + shift  (residual folded into MLP head, no hin needed)
__global__ __launch_bounds__(256) void bn_apply(
    float* __restrict__ x, const float* __restrict__ sums)
{
  int i = blockIdx.x * 256 + threadIdx.x;
  int j = i & 127;
  x[i] = x[i] * sums[256 + j] + sums[384 + j];
}

// ---------------------------------------------------------------------------
// Residual fold constants: E2 = embW @ mlpW  [128][40],
//                          c2 = mlpB + embB @ mlpW  [40]
// One block, 256 threads, 20 E2 entries each.
// ---------------------------------------------------------------------------
__global__ void prep_e2(const float* __restrict__ embW,
                        const float* __restrict__ embB,
                        const float* __restrict__ mlpW,
                        const float* __restrict__ mlpB,
                        float* __restrict__ e2, float* __restrict__ c2)
{
  int tid = threadIdx.x;
#pragma unroll
  for (int t = 0; t < 20; t++) {
    int idx = tid * 20 + t;        // 0..5119
    int f = idx / 40, j = idx - f * 40;
    float s = 0.f;
    for (int k = 0; k < 128; k++)
      s = fmaf(embW[f * 128 + k], mlpW[k * 40 + j], s);
    e2[idx] = s;
  }
  if (tid < 40) {
    float s = mlpB[tid];
    for (int k = 0; k < 128; k++)
      s = fmaf(embB[k], mlpW[k * 40 + tid], s);
    c2[tid] = s;
  }
}

// ---------------------------------------------------------------------------
extern "C" void kernel_launch(void* const* d_in, const int* in_sizes, int n_in,
                              void* d_out, int out_size, void* d_ws, size_t ws_size,
                              hipStream_t stream)
{
  const float* h     = (const float*)d_in[0];
  const int*   ei    = (const int*)d_in[1];     // edge_index [2][E] (int32 per harness)
  const float* ew    = (const float*)d_in[2];
  const float* embW  = (const float*)d_in[3];
  const float* embB  = (const float*)d_in[4];
  const float* convW = (const float*)d_in[5];   // [3][128][128]
  const float* Wih   = (const float*)d_in[6];   // [384][128]
  const float* Whh   = (const float*)d_in[7];
  const float* bih   = (const float*)d_in[8];
  const float* bhh   = (const float*)d_in[9];
  const float* gamma = (const float*)d_in[10];
  const float* beta  = (const float*)d_in[11];
  const float* mlpW  = (const float*)d_in[12];  // [128][40]
  const float* mlpB  = (const float*)d_in[13];
  float* out = (float*)d_out;

  float* ws = (float*)d_ws;
  const size_t NH = (size_t)N_NODES * HDIM;     // 12.8M floats
  float* x    = ws;                 // [N,128]
  float* m    = ws + NH;            // [N,128] conv output
  float* agg  = ws + 2 * NH;        // [N,128] scatter target
  float* sums = ws + 3 * NH;        // 8192 floats: stats(512) | e2(5120) | c2(40)
  float* e2   = sums + 512;
  float* c2   = sums + 512 + 5120;
  float* chunkBase = ws + 3 * NH + 8192;

  // gi/gh chunk size adapted to workspace budget (ws_size constant -> same
  // work every call; graph-capture safe). Floor usage: 3*NH*4 + 32KB = 154MB.
  long long avail = (long long)(ws_size / 4) - (long long)(3 * NH + 8192);
  long long chll = avail / (2 * 384);
  if (chll > N_NODES) chll = N_NODES;
  chll = (chll / 64) * 64;
  if (chll < 64) chll = 64;                     // last-resort (ws too small anyway)
  const int CH = (int)chll;
  float* gi = chunkBase;                        // [CH][384]
  float* gh = chunkBase + (size_t)CH * 384;     // [CH][384]

  dim3 blk(256);
  const int MB = (N_NODES + 63) / 64;           // 1563 row-blocks

  // residual-fold constants (independent; run first)
  prep_e2<<<1, 256, 0, stream>>>(embW, embB, mlpW, mlpB, e2, c2);

  // embedding: x = h @ embW + embB
  gemm_k128<false, false><<<dim3(MB, 1), blk, 0, stream>>>(h, embW, embB, x, N_NODES, 128);

  for (int l = 0; l < 3; l++) {
    // m = x @ convW[l]
    gemm_k128<false, false><<<dim3(MB, 1), blk, 0, stream>>>(
        x, convW + (size_t)l * HDIM * HDIM, nullptr, m, N_NODES, 128);
    // agg = segment_sum(w * m[src], dst)
    zero_f32<<<(int)(NH / 256), blk, 0, stream>>>(agg, (int)NH);
    scatter_add<<<N_EDGES / 4, blk, 0, stream>>>(m, ei, ew, agg);
    // GRU, chunked over node rows to bound gi/gh footprint
    for (int r0 = 0; r0 < N_NODES; r0 += CH) {
      int Mc = N_NODES - r0; if (Mc > CH) Mc = CH;
      int gb = (Mc + 63) / 64;
      gemm_k128<true, false><<<dim3(gb, 3), blk, 0, stream>>>(
          agg + (size_t)r0 * HDIM, Wih, bih, gi, Mc, 384);
      gemm_k128<true, false><<<dim3(gb, 3), blk, 0, stream>>>(
          x + (size_t)r0 * HDIM, Whh, bhh, gh, Mc, 384);
      int total = Mc * HDIM;
      gru_elem<<<(total + 255) / 256, blk, 0, stream>>>(
          gi, gh, x + (size_t)r0 * HDIM, total);
    }
  }

  // BatchNorm (training stats); residual folded into the MLP head below
  zero_f32<<<2, blk, 0, stream>>>(sums, 512);
  bn_stats<<<(N_NODES + 127) / 128, blk, 0, stream>>>(x, sums);
  bn_finalize<<<1, 128, 0, stream>>>(sums, gamma, beta);
  bn_apply<<<(int)(NH / 256), blk, 0, stream>>>(x, sums);

  // out = BN(x) @ mlpW + c2 ; then out += h @ E2   (residual fold)
  gemm_k128<false, false><<<dim3(MB, 1), blk, 0, stream>>>(x, mlpW, c2, out, N_NODES, 40);
  gemm_k128<false, true><<<dim3(MB, 1), blk, 0, stream>>>(h, e2, nullptr, out, N_NODES, 40);
}

// Round 3
// 2858.574 us; speedup vs baseline: 1.9928x; 1.9928x over previous
//
#include <hip/hip_runtime.h>
#include <math.h>

#define N_NODES 100000
#define N_EDGES 3200000
#define HDIM 128

// ---------------------------------------------------------------------------
__global__ __launch_bounds__(256) void zero_i32(int* __restrict__ p, int n) {
  int i = blockIdx.x * 256 + threadIdx.x;
  if (i < n) p[i] = 0;
}
__global__ __launch_bounds__(256) void zero_f32(float* __restrict__ p, int n) {
  int i = blockIdx.x * 256 + threadIdx.x;
  if (i < n) p[i] = 0.f;
}

// ---------------------------------------------------------------------------
// Tiled fp32 GEMM, K fixed at 128. Y[n][j] = sum_k A[n][k] * W(k,j) + bias[j]
//  BT=false: W stored [128][OUT] row-major (W[k][j])
//  BT=true : W stored [OUT][128] row-major (W[j][k])   (y = A@W^T)
//  ACC=true: Y += result
// Block: 256 threads, tile 64 rows x 128 cols, thread tile 4x8.
// ---------------------------------------------------------------------------
template<bool BT, bool ACC>
__global__ __launch_bounds__(256) void gemm_k128(
    const float* __restrict__ A, const float* __restrict__ W,
    const float* __restrict__ bias, float* __restrict__ Y,
    int M, int OUT)
{
  __shared__ alignas(16) float lds_a[32 * 68];    // [kk][row], stride 68 (pad)
  __shared__ alignas(16) float lds_b[32 * 132];   // [kk][col], stride 132 (pad)
  const int tid = threadIdx.x;
  const int tx = tid & 15;          // col group (8 cols each)
  const int ty = tid >> 4;          // row group (4 rows each)
  const int rowBase = blockIdx.x * 64;
  const int colBase = blockIdx.y * 128;

  float acc[4][8];
#pragma unroll
  for (int r = 0; r < 4; r++)
#pragma unroll
    for (int c = 0; c < 8; c++) acc[r][c] = 0.f;

  for (int k0 = 0; k0 < 128; k0 += 32) {
#pragma unroll
    for (int i = 0; i < 2; i++) {
      int idx = tid + i * 256;          // 0..511
      int r   = idx >> 3;               // 0..63
      int kk  = (idx & 7) << 2;         // 0,4,..,28
      int gr  = rowBase + r;
      float4 v = make_float4(0.f, 0.f, 0.f, 0.f);
      if (gr < M) v = *(const float4*)(A + (size_t)gr * HDIM + k0 + kk);
      lds_a[(kk + 0) * 68 + r] = v.x;
      lds_a[(kk + 1) * 68 + r] = v.y;
      lds_a[(kk + 2) * 68 + r] = v.z;
      lds_a[(kk + 3) * 68 + r] = v.w;
    }
    if (!BT) {
#pragma unroll
      for (int i = 0; i < 4; i++) {
        int idx = tid + i * 256;        // 0..1023
        int kk  = idx >> 5;             // 0..31
        int j   = (idx & 31) << 2;      // 0..124
        int gj  = colBase + j;
        float4 v = make_float4(0.f, 0.f, 0.f, 0.f);
        if (gj < OUT) v = *(const float4*)(W + (size_t)(k0 + kk) * OUT + gj);
        *((float4*)&lds_b[kk * 132 + j]) = v;
      }
    } else {
#pragma unroll
      for (int i = 0; i < 4; i++) {
        int idx = tid + i * 256;        // 0..1023
        int j   = idx >> 3;             // 0..127
        int k4  = (idx & 7) << 2;       // 0..28
        int gj  = colBase + j;
        float4 v = make_float4(0.f, 0.f, 0.f, 0.f);
        if (gj < OUT) v = *(const float4*)(W + (size_t)gj * HDIM + k0 + k4);
        lds_b[(k4 + 0) * 132 + j] = v.x;
        lds_b[(k4 + 1) * 132 + j] = v.y;
        lds_b[(k4 + 2) * 132 + j] = v.z;
        lds_b[(k4 + 3) * 132 + j] = v.w;
      }
    }
    __syncthreads();
#pragma unroll 8
    for (int kk = 0; kk < 32; kk++) {
      float4 a4 = *(const float4*)&lds_a[kk * 68 + ty * 4];
      float4 b0 = *(const float4*)&lds_b[kk * 132 + tx * 8];
      float4 b1 = *(const float4*)&lds_b[kk * 132 + tx * 8 + 4];
      float av[4] = {a4.x, a4.y, a4.z, a4.w};
      float bv[8] = {b0.x, b0.y, b0.z, b0.w, b1.x, b1.y, b1.z, b1.w};
#pragma unroll
      for (int r = 0; r < 4; r++)
#pragma unroll
        for (int c = 0; c < 8; c++)
          acc[r][c] = fmaf(av[r], bv[c], acc[r][c]);
    }
    __syncthreads();
  }

  int col = colBase + tx * 8;
  if (col >= OUT) return;
  float bv[8];
#pragma unroll
  for (int c = 0; c < 8; c++) bv[c] = bias ? bias[col + c] : 0.f;
#pragma unroll
  for (int r = 0; r < 4; r++) {
    int gr = rowBase + ty * 4 + r;
    if (gr >= M) continue;
    float* yp = Y + (size_t)gr * OUT + col;
    float4 o0 = make_float4(acc[r][0] + bv[0], acc[r][1] + bv[1],
                            acc[r][2] + bv[2], acc[r][3] + bv[3]);
    float4 o1 = make_float4(acc[r][4] + bv[4], acc[r][5] + bv[5],
                            acc[r][6] + bv[6], acc[r][7] + bv[7]);
    if (ACC) {
      float4 y0 = *(float4*)yp;
      float4 y1 = *(float4*)(yp + 4);
      o0.x += y0.x; o0.y += y0.y; o0.z += y0.z; o0.w += y0.w;
      o1.x += y1.x; o1.y += y1.y; o1.z += y1.z; o1.w += y1.w;
    }
    *(float4*)yp       = o0;
    *(float4*)(yp + 4) = o1;
  }
}

// ---------------------------------------------------------------------------
// CSR build (by destination). Graph is layer-invariant -> build once per call.
// ---------------------------------------------------------------------------
__global__ __launch_bounds__(256) void csr_hist(
    const int* __restrict__ ei, int* __restrict__ deg)
{
  int e = blockIdx.x * 256 + threadIdx.x;
  if (e < N_EDGES) atomicAdd(&deg[ei[N_EDGES + e]], 1);
}

// single-block exclusive scan over deg[N] -> rowptr[N+1]
__global__ __launch_bounds__(1024) void csr_scan(
    const int* __restrict__ deg, int* __restrict__ rowptr)
{
  __shared__ int lds[1024];
  __shared__ int s_carry;
  int tid = threadIdx.x;
  if (tid == 0) s_carry = 0;
  __syncthreads();
  for (int base = 0; base < N_NODES; base += 1024) {
    int i = base + tid;
    int v = (i < N_NODES) ? deg[i] : 0;
    lds[tid] = v;
    __syncthreads();
    for (int off = 1; off < 1024; off <<= 1) {
      int t = (tid >= off) ? lds[tid - off] : 0;
      __syncthreads();
      lds[tid] += t;
      __syncthreads();
    }
    int carry = s_carry;
    if (i < N_NODES) rowptr[i] = carry + lds[tid] - v;   // exclusive
    __syncthreads();
    if (tid == 1023) s_carry = carry + lds[1023];
    __syncthreads();
  }
  if (tid == 0) rowptr[N_NODES] = s_carry;               // == E
}

__global__ __launch_bounds__(256) void csr_fill(
    const int* __restrict__ ei, const float* __restrict__ ew,
    const int* __restrict__ rowptr, int* __restrict__ cnt,
    int* __restrict__ esrc, float* __restrict__ eww)
{
  int e = blockIdx.x * 256 + threadIdx.x;
  if (e >= N_EDGES) return;
  int d = ei[N_EDGES + e];
  int pos = rowptr[d] + atomicAdd(&cnt[d], 1);
  esrc[pos] = ei[e];
  eww[pos]  = ew[e];
}

// ---------------------------------------------------------------------------
// Pull aggregation: z[n] = sum_{e in row n} w_e * x[src_e].  One wave/node,
// 2 cols/lane, register accumulation, single coalesced write.
// ---------------------------------------------------------------------------
__global__ __launch_bounds__(256) void agg_pull(
    const float* __restrict__ x, const int* __restrict__ rowptr,
    const int* __restrict__ esrc, const float* __restrict__ eww,
    float* __restrict__ z)
{
  int node = blockIdx.x * 4 + (threadIdx.x >> 6);
  if (node >= N_NODES) return;
  int lane = threadIdx.x & 63;
  int s0 = rowptr[node], s1 = rowptr[node + 1];
  float v0 = 0.f, v1 = 0.f;
  int e = s0;
  for (; e + 1 < s1; e += 2) {          // 2-edge unroll: overlap row-gather latency
    int   sa = esrc[e],   sb = esrc[e + 1];
    float wa = eww[e],    wb = eww[e + 1];
    const float* xa = x + (size_t)sa * HDIM;
    const float* xb = x + (size_t)sb * HDIM;
    float a0 = xa[lane], a1 = xa[64 + lane];
    float b0 = xb[lane], b1 = xb[64 + lane];
    v0 = fmaf(wa, a0, v0); v1 = fmaf(wa, a1, v1);
    v0 = fmaf(wb, b0, v0); v1 = fmaf(wb, b1, v1);
  }
  if (e < s1) {
    int s = esrc[e]; float w = eww[e];
    const float* xr = x + (size_t)s * HDIM;
    v0 = fmaf(w, xr[lane], v0);
    v1 = fmaf(w, xr[64 + lane], v1);
  }
  z[(size_t)node * HDIM + lane]      = v0;
  z[(size_t)node * HDIM + 64 + lane] = v1;
}

// ---------------------------------------------------------------------------
// GRU elementwise update (in place on x chunk). gi/gh are [Mc][384] (r|z|n).
// ---------------------------------------------------------------------------
__global__ __launch_bounds__(256) void gru_elem(
    const float* __restrict__ gi, const float* __restrict__ gh,
    float* __restrict__ x, int total)
{
  int i = blockIdx.x * 256 + threadIdx.x;
  if (i >= total) return;
  int n = i >> 7, j = i & 127;
  size_t b = (size_t)n * 384 + j;
  float ir = gi[b], iz = gi[b + 128], inn = gi[b + 256];
  float hr = gh[b], hz = gh[b + 128], hn  = gh[b + 256];
  float r  = 1.f / (1.f + __expf(-(ir + hr)));
  float z  = 1.f / (1.f + __expf(-(iz + hz)));
  float nn = tanhf(inn + r * hn);
  float xo = x[i];
  x[i] = (1.f - z) * nn + z * xo;
}

// ---------------------------------------------------------------------------
// BatchNorm
// ---------------------------------------------------------------------------
__global__ __launch_bounds__(256) void bn_stats(
    const float* __restrict__ x, float* __restrict__ sums)
{
  __shared__ float ls[256], lq[256];
  int tid  = threadIdx.x;
  int col  = tid & 127, half = tid >> 7;
  int r0   = blockIdx.x * 128;
  int rend = min(N_NODES, r0 + 128);
  float s = 0.f, q = 0.f;
  for (int r = r0 + half; r < rend; r += 2) {
    float v = x[(size_t)r * HDIM + col];
    s += v; q += v * v;
  }
  ls[tid] = s; lq[tid] = q;
  __syncthreads();
  if (tid < 128) {
    atomicAdd(&sums[col],       ls[tid] + ls[tid + 128]);
    atomicAdd(&sums[128 + col], lq[tid] + lq[tid + 128]);
  }
}

__global__ void bn_finalize(float* __restrict__ sums,
                            const float* __restrict__ gamma,
                            const float* __restrict__ beta)
{
  int j = threadIdx.x;           // 128 threads
  float mean = sums[j] / (float)N_NODES;
  float var  = sums[128 + j] / (float)N_NODES - mean * mean;
  float inv  = rsqrtf(var + 1e-5f);
  sums[256 + j] = gamma[j] * inv;                    // scale
  sums[384 + j] = beta[j] - mean * gamma[j] * inv;   // shift
}

__global__ __launch_bounds__(256) void bn_apply(
    float* __restrict__ x, const float* __restrict__ sums)
{
  int i = blockIdx.x * 256 + threadIdx.x;
  int j = i & 127;
  x[i] = x[i] * sums[256 + j] + sums[384 + j];
}

// ---------------------------------------------------------------------------
// Residual fold constants: E2 = embW @ mlpW  [128][40], c2 = mlpB + embB@mlpW
// ---------------------------------------------------------------------------
__global__ void prep_e2(const float* __restrict__ embW,
                        const float* __restrict__ embB,
                        const float* __restrict__ mlpW,
                        const float* __restrict__ mlpB,
                        float* __restrict__ e2, float* __restrict__ c2)
{
  int tid = threadIdx.x;
#pragma unroll
  for (int t = 0; t < 20; t++) {
    int idx = tid * 20 + t;        // 0..5119
    int f = idx / 40, j = idx - f * 40;
    float s = 0.f;
    for (int k = 0; k < 128; k++)
      s = fmaf(embW[f * 128 + k], mlpW[k * 40 + j], s);
    e2[idx] = s;
  }
  if (tid < 40) {
    float s = mlpB[tid];
    for (int k = 0; k < 128; k++)
      s = fmaf(embB[k], mlpW[k * 40 + tid], s);
    c2[tid] = s;
  }
}

// ---------------------------------------------------------------------------
extern "C" void kernel_launch(void* const* d_in, const int* in_sizes, int n_in,
                              void* d_out, int out_size, void* d_ws, size_t ws_size,
                              hipStream_t stream)
{
  const float* h     = (const float*)d_in[0];
  const int*   ei    = (const int*)d_in[1];     // edge_index [2][E] int32
  const float* ew    = (const float*)d_in[2];
  const float* embW  = (const float*)d_in[3];
  const float* embB  = (const float*)d_in[4];
  const float* convW = (const float*)d_in[5];   // [3][128][128]
  const float* Wih   = (const float*)d_in[6];   // [384][128]
  const float* Whh   = (const float*)d_in[7];
  const float* bih   = (const float*)d_in[8];
  const float* bhh   = (const float*)d_in[9];
  const float* gamma = (const float*)d_in[10];
  const float* beta  = (const float*)d_in[11];
  const float* mlpW  = (const float*)d_in[12];  // [128][40]
  const float* mlpB  = (const float*)d_in[13];
  float* out = (float*)d_out;

  float* ws = (float*)d_ws;
  const size_t NH = (size_t)N_NODES * HDIM;     // 12.8M floats
  float* x      = ws;                            // [N,128]
  float* z      = ws + NH;                       // [N,128] aggregated
  int*   rowptr = (int*)(ws + 2 * NH);           // N+4
  int*   cnt    = rowptr + N_NODES + 4;          // N
  int*   deg    = cnt + N_NODES;                 // N
  int*   esrc   = deg + N_NODES;                 // E (CSR src, dst-sorted)
  float* eww    = (float*)(esrc + N_EDGES);      // E (CSR weights)
  float* Wfold  = eww + N_EDGES;                 // 3*128*384
  float* sums   = Wfold + 3 * 128 * 384;         // 512
  float* e2     = sums + 512;                    // 5120
  float* c2     = e2 + 5120;                     // 64 (pad)
  float* chunkBase = c2 + 64;
  // fixed footprint: ~130 MB

  long long avail = (long long)(ws_size / 4) - (long long)(chunkBase - ws);
  long long chll = avail / (2 * 384);
  if (chll > N_NODES) chll = N_NODES;
  chll = (chll / 64) * 64;
  if (chll < 64) chll = 64;
  const int CH = (int)chll;
  float* gi = chunkBase;                        // [CH][384]
  float* gh = chunkBase + (size_t)CH * 384;     // [CH][384]

  dim3 blk(256);
  const int MB = (N_NODES + 63) / 64;           // row-blocks for N
  const int EB = (N_EDGES + 255) / 256;         // edge blocks

  // ---- constants: residual fold + conv-into-Wih folds (tiny GEMMs) ----
  prep_e2<<<1, 256, 0, stream>>>(embW, embB, mlpW, mlpB, e2, c2);
  for (int l = 0; l < 3; l++)
    gemm_k128<true, false><<<dim3(2, 3), blk, 0, stream>>>(
        convW + (size_t)l * HDIM * HDIM, Wih, nullptr,
        Wfold + (size_t)l * HDIM * 384, 128, 384);

  // ---- CSR build (once; graph is layer-invariant) ----
  zero_i32<<<(2 * N_NODES + 255) / 256, blk, 0, stream>>>(cnt, 2 * N_NODES); // cnt+deg
  csr_hist<<<EB, blk, 0, stream>>>(ei, deg);
  csr_scan<<<1, 1024, 0, stream>>>(deg, rowptr);
  csr_fill<<<EB, blk, 0, stream>>>(ei, ew, rowptr, cnt, esrc, eww);

  // ---- embedding: x = h @ embW + embB ----
  gemm_k128<false, false><<<dim3(MB, 1), blk, 0, stream>>>(h, embW, embB, x, N_NODES, 128);

  for (int l = 0; l < 3; l++) {
    // z = A x   (weighted pull aggregation)
    agg_pull<<<(N_NODES + 3) / 4, blk, 0, stream>>>(x, rowptr, esrc, eww, z);
    // GRU, chunked over node rows (gi = z@Fold_l + bih ; gh = x@Whh^T + bhh)
    for (int r0 = 0; r0 < N_NODES; r0 += CH) {
      int Mc = N_NODES - r0; if (Mc > CH) Mc = CH;
      int gb = (Mc + 63) / 64;
      gemm_k128<false, false><<<dim3(gb, 3), blk, 0, stream>>>(
          z + (size_t)r0 * HDIM, Wfold + (size_t)l * HDIM * 384, bih, gi, Mc, 384);
      gemm_k128<true, false><<<dim3(gb, 3), blk, 0, stream>>>(
          x + (size_t)r0 * HDIM, Whh, bhh, gh, Mc, 384);
      int total = Mc * HDIM;
      gru_elem<<<(total + 255) / 256, blk, 0, stream>>>(
          gi, gh, x + (size_t)r0 * HDIM, total);
    }
  }

  // ---- BatchNorm (training stats); residual folded into head ----
  zero_f32<<<2, blk, 0, stream>>>(sums, 512);
  bn_stats<<<(N_NODES + 127) / 128, blk, 0, stream>>>(x, sums);
  bn_finalize<<<1, 128, 0, stream>>>(sums, gamma, beta);
  bn_apply<<<(int)(NH / 256), blk, 0, stream>>>(x, sums);

  // ---- head: out = BN(x)@mlpW + c2 ; out += h@E2 (residual) ----
  gemm_k128<false, false><<<dim3(MB, 1), blk, 0, stream>>>(x, mlpW, c2, out, N_NODES, 40);
  gemm_k128<false, true><<<dim3(MB, 1), blk, 0, stream>>>(h, e2, nullptr, out, N_NODES, 40);
}

// Round 4
// 2145.171 us; speedup vs baseline: 2.6555x; 1.3326x over previous
//
#include <hip/hip_runtime.h>
#include <math.h>

#define N_NODES 100000
#define N_EDGES 3200000
#define HDIM 128

typedef __attribute__((ext_vector_type(8))) short bf16x8;
typedef __attribute__((ext_vector_type(4))) float f32x4;

__device__ __forceinline__ unsigned short f2bf(float f) {
  union { float f; unsigned u; } v; v.f = f;
  unsigned r = v.u + 0x7fffu + ((v.u >> 16) & 1u);
  return (unsigned short)(r >> 16);
}
__device__ __forceinline__ float bflo(unsigned p) {
  union { unsigned u; float f; } v; v.u = p << 16; return v.f;
}
__device__ __forceinline__ float bfhi(unsigned p) {
  union { unsigned u; float f; } v; v.u = p & 0xffff0000u; return v.f;
}

// ---------------------------------------------------------------------------
__global__ __launch_bounds__(256) void zero_i32(int* __restrict__ p, int n) {
  int i = blockIdx.x * 256 + threadIdx.x;
  if (i < n) p[i] = 0;
}
__global__ __launch_bounds__(256) void zero_f32(float* __restrict__ p, int n) {
  int i = blockIdx.x * 256 + threadIdx.x;
  if (i < n) p[i] = 0.f;
}
// pack 2 consecutive floats -> 2 bf16 in one u32
__global__ __launch_bounds__(256) void f32_to_bf16_pack(
    const float* __restrict__ src, unsigned* __restrict__ dst, int n2) {
  int i = blockIdx.x * 256 + threadIdx.x;
  if (i >= n2) return;
  dst[i] = (unsigned)f2bf(src[2 * i]) | ((unsigned)f2bf(src[2 * i + 1]) << 16);
}

// ---------------------------------------------------------------------------
// Tiled fp32 GEMM, K fixed at 128 (emb, head, weight folds).
// ---------------------------------------------------------------------------
template<bool BT, bool ACC>
__global__ __launch_bounds__(256) void gemm_k128(
    const float* __restrict__ A, const float* __restrict__ W,
    const float* __restrict__ bias, float* __restrict__ Y,
    int M, int OUT)
{
  __shared__ alignas(16) float lds_a[32 * 68];
  __shared__ alignas(16) float lds_b[32 * 132];
  const int tid = threadIdx.x;
  const int tx = tid & 15;
  const int ty = tid >> 4;
  const int rowBase = blockIdx.x * 64;
  const int colBase = blockIdx.y * 128;

  float acc[4][8];
#pragma unroll
  for (int r = 0; r < 4; r++)
#pragma unroll
    for (int c = 0; c < 8; c++) acc[r][c] = 0.f;

  for (int k0 = 0; k0 < 128; k0 += 32) {
#pragma unroll
    for (int i = 0; i < 2; i++) {
      int idx = tid + i * 256;
      int r   = idx >> 3;
      int kk  = (idx & 7) << 2;
      int gr  = rowBase + r;
      float4 v = make_float4(0.f, 0.f, 0.f, 0.f);
      if (gr < M) v = *(const float4*)(A + (size_t)gr * HDIM + k0 + kk);
      lds_a[(kk + 0) * 68 + r] = v.x;
      lds_a[(kk + 1) * 68 + r] = v.y;
      lds_a[(kk + 2) * 68 + r] = v.z;
      lds_a[(kk + 3) * 68 + r] = v.w;
    }
    if (!BT) {
#pragma unroll
      for (int i = 0; i < 4; i++) {
        int idx = tid + i * 256;
        int kk  = idx >> 5;
        int j   = (idx & 31) << 2;
        int gj  = colBase + j;
        float4 v = make_float4(0.f, 0.f, 0.f, 0.f);
        if (gj < OUT) v = *(const float4*)(W + (size_t)(k0 + kk) * OUT + gj);
        *((float4*)&lds_b[kk * 132 + j]) = v;
      }
    } else {
#pragma unroll
      for (int i = 0; i < 4; i++) {
        int idx = tid + i * 256;
        int j   = idx >> 3;
        int k4  = (idx & 7) << 2;
        int gj  = colBase + j;
        float4 v = make_float4(0.f, 0.f, 0.f, 0.f);
        if (gj < OUT) v = *(const float4*)(W + (size_t)gj * HDIM + k0 + k4);
        lds_b[(k4 + 0) * 132 + j] = v.x;
        lds_b[(k4 + 1) * 132 + j] = v.y;
        lds_b[(k4 + 2) * 132 + j] = v.z;
        lds_b[(k4 + 3) * 132 + j] = v.w;
      }
    }
    __syncthreads();
#pragma unroll 8
    for (int kk = 0; kk < 32; kk++) {
      float4 a4 = *(const float4*)&lds_a[kk * 68 + ty * 4];
      float4 b0 = *(const float4*)&lds_b[kk * 132 + tx * 8];
      float4 b1 = *(const float4*)&lds_b[kk * 132 + tx * 8 + 4];
      float av[4] = {a4.x, a4.y, a4.z, a4.w};
      float bv[8] = {b0.x, b0.y, b0.z, b0.w, b1.x, b1.y, b1.z, b1.w};
#pragma unroll
      for (int r = 0; r < 4; r++)
#pragma unroll
        for (int c = 0; c < 8; c++)
          acc[r][c] = fmaf(av[r], bv[c], acc[r][c]);
    }
    __syncthreads();
  }

  int col = colBase + tx * 8;
  if (col >= OUT) return;
  float bv[8];
#pragma unroll
  for (int c = 0; c < 8; c++) bv[c] = bias ? bias[col + c] : 0.f;
#pragma unroll
  for (int r = 0; r < 4; r++) {
    int gr = rowBase + ty * 4 + r;
    if (gr >= M) continue;
    float* yp = Y + (size_t)gr * OUT + col;
    float4 o0 = make_float4(acc[r][0] + bv[0], acc[r][1] + bv[1],
                            acc[r][2] + bv[2], acc[r][3] + bv[3]);
    float4 o1 = make_float4(acc[r][4] + bv[4], acc[r][5] + bv[5],
                            acc[r][6] + bv[6], acc[r][7] + bv[7]);
    if (ACC) {
      float4 y0 = *(float4*)yp;
      float4 y1 = *(float4*)(yp + 4);
      o0.x += y0.x; o0.y += y0.y; o0.z += y0.z; o0.w += y0.w;
      o1.x += y1.x; o1.y += y1.y; o1.z += y1.z; o1.w += y1.w;
    }
    *(float4*)yp       = o0;
    *(float4*)(yp + 4) = o1;
  }
}

// ---------------------------------------------------------------------------
// CSR build (by destination), edges packed as int2{src, w_bits}.
// ---------------------------------------------------------------------------
__global__ __launch_bounds__(256) void csr_hist(
    const int* __restrict__ ei, int* __restrict__ deg)
{
  int e = blockIdx.x * 256 + threadIdx.x;
  if (e < N_EDGES) atomicAdd(&deg[ei[N_EDGES + e]], 1);
}

__global__ __launch_bounds__(1024) void csr_scan(
    const int* __restrict__ deg, int* __restrict__ rowptr)
{
  __shared__ int lds[1024];
  __shared__ int s_carry;
  int tid = threadIdx.x;
  if (tid == 0) s_carry = 0;
  __syncthreads();
  for (int base = 0; base < N_NODES; base += 1024) {
    int i = base + tid;
    int v = (i < N_NODES) ? deg[i] : 0;
    lds[tid] = v;
    __syncthreads();
    for (int off = 1; off < 1024; off <<= 1) {
      int t = (tid >= off) ? lds[tid - off] : 0;
      __syncthreads();
      lds[tid] += t;
      __syncthreads();
    }
    int carry = s_carry;
    if (i < N_NODES) rowptr[i] = carry + lds[tid] - v;
    __syncthreads();
    if (tid == 1023) s_carry = carry + lds[1023];
    __syncthreads();
  }
  if (tid == 0) rowptr[N_NODES] = s_carry;
}

__global__ __launch_bounds__(256) void csr_fill(
    const int* __restrict__ ei, const float* __restrict__ ew,
    const int* __restrict__ rowptr, int* __restrict__ cnt,
    int2* __restrict__ epak)
{
  int e = blockIdx.x * 256 + threadIdx.x;
  if (e >= N_EDGES) return;
  int d = ei[N_EDGES + e];
  int pos = rowptr[d] + atomicAdd(&cnt[d], 1);
  epak[pos] = make_int2(ei[e], __float_as_int(ew[e]));
}

// ---------------------------------------------------------------------------
// Pull aggregation on bf16 x: z[n] = sum w_e * x[src_e], fp32 accumulate,
// bf16 packed output (z is only ever an MFMA A-operand). One wave/node,
// lane covers cols {2*lane, 2*lane+1} via one packed u32 per row.
// ---------------------------------------------------------------------------
__global__ __launch_bounds__(256) void agg_pull(
    const unsigned* __restrict__ xbp, const int* __restrict__ rowptr,
    const int2* __restrict__ epak, unsigned* __restrict__ zbp)
{
  int node = blockIdx.x * 4 + (threadIdx.x >> 6);
  if (node >= N_NODES) return;
  int lane = threadIdx.x & 63;
  int s0 = rowptr[node], s1 = rowptr[node + 1];
  float v0 = 0.f, v1 = 0.f;
  int e = s0;
  for (; e + 3 < s1; e += 4) {
    int2 e0 = epak[e], e1 = epak[e + 1], e2 = epak[e + 2], e3 = epak[e + 3];
    unsigned p0 = xbp[(size_t)e0.x * 64 + lane];
    unsigned p1 = xbp[(size_t)e1.x * 64 + lane];
    unsigned p2 = xbp[(size_t)e2.x * 64 + lane];
    unsigned p3 = xbp[(size_t)e3.x * 64 + lane];
    float w0 = __int_as_float(e0.y), w1 = __int_as_float(e1.y);
    float w2 = __int_as_float(e2.y), w3 = __int_as_float(e3.y);
    v0 = fmaf(w0, bflo(p0), v0); v1 = fmaf(w0, bfhi(p0), v1);
    v0 = fmaf(w1, bflo(p1), v0); v1 = fmaf(w1, bfhi(p1), v1);
    v0 = fmaf(w2, bflo(p2), v0); v1 = fmaf(w2, bfhi(p2), v1);
    v0 = fmaf(w3, bflo(p3), v0); v1 = fmaf(w3, bfhi(p3), v1);
  }
  for (; e < s1; e++) {
    int2 ep = epak[e];
    unsigned p = xbp[(size_t)ep.x * 64 + lane];
    float w = __int_as_float(ep.y);
    v0 = fmaf(w, bflo(p), v0); v1 = fmaf(w, bfhi(p), v1);
  }
  zbp[(size_t)node * 64 + lane] =
      (unsigned)f2bf(v0) | ((unsigned)f2bf(v1) << 16);
}

// ---------------------------------------------------------------------------
// Fused GRU layer (bf16 MFMA): per wave 16 rows x 128 gate-cols.
//  phase 0: A = z (agg, bf16), B = Fb = (convW_l @ Wih^T) as [gate][col][k]
//           -> acc_r, acc_z, acc_in
//  phase 1: A = x (bf16),      B = Wb = Whh as [gate][col][k]
//           -> acc_r, acc_z, acc_hn
//  epilogue: GRU gates, x updated in place (fp32 + bf16 mirror).
// No LDS, no barriers; waves touch only their own 16 rows.
// ---------------------------------------------------------------------------
__global__ __launch_bounds__(256) void gru_fused(
    const short* __restrict__ zb, short* __restrict__ xb,
    float* __restrict__ x,
    const short* __restrict__ Fb, const short* __restrict__ Wb,
    const float* __restrict__ bih, const float* __restrict__ bhh)
{
  const int wave = threadIdx.x >> 6, lane = threadIdx.x & 63;
  const int m  = lane & 15;          // A row / B col / C col within tile
  const int g4 = lane >> 4;          // k-group
  const int rowBase = blockIdx.x * 64 + wave * 16;
  int arow = rowBase + m;
  int arowc = arow < N_NODES ? arow : N_NODES - 1;

  f32x4 aR[8], aZ[8], aN[8], aH[8];
#pragma unroll
  for (int t = 0; t < 8; t++) {
    aR[t] = (f32x4){0.f, 0.f, 0.f, 0.f};
    aZ[t] = (f32x4){0.f, 0.f, 0.f, 0.f};
    aN[t] = (f32x4){0.f, 0.f, 0.f, 0.f};
    aH[t] = (f32x4){0.f, 0.f, 0.f, 0.f};
  }

  const short* az = zb + (size_t)arowc * 128 + g4 * 8;
  const short* ax = xb + (size_t)arowc * 128 + g4 * 8;

  // ---- phase 0: z @ F  -> r,z,i_n ----
#pragma unroll
  for (int ks = 0; ks < 4; ks++) {
    bf16x8 a = *(const bf16x8*)(az + ks * 32);
    int bo = m * 128 + ks * 32 + g4 * 8;
#pragma unroll
    for (int t = 0; t < 8; t++) {
      const short* bp = Fb + t * 2048 + bo;           // t*16 cols * 128 k
      bf16x8 br = *(const bf16x8*)(bp);
      bf16x8 bz = *(const bf16x8*)(bp + 16384);
      bf16x8 bn = *(const bf16x8*)(bp + 32768);
      aR[t] = __builtin_amdgcn_mfma_f32_16x16x32_bf16(a, br, aR[t], 0, 0, 0);
      aZ[t] = __builtin_amdgcn_mfma_f32_16x16x32_bf16(a, bz, aZ[t], 0, 0, 0);
      aN[t] = __builtin_amdgcn_mfma_f32_16x16x32_bf16(a, bn, aN[t], 0, 0, 0);
    }
  }
  // ---- phase 1: x @ Whh^T -> r,z,h_n ----
#pragma unroll
  for (int ks = 0; ks < 4; ks++) {
    bf16x8 a = *(const bf16x8*)(ax + ks * 32);
    int bo = m * 128 + ks * 32 + g4 * 8;
#pragma unroll
    for (int t = 0; t < 8; t++) {
      const short* bp = Wb + t * 2048 + bo;
      bf16x8 br = *(const bf16x8*)(bp);
      bf16x8 bz = *(const bf16x8*)(bp + 16384);
      bf16x8 bn = *(const bf16x8*)(bp + 32768);
      aR[t] = __builtin_amdgcn_mfma_f32_16x16x32_bf16(a, br, aR[t], 0, 0, 0);
      aZ[t] = __builtin_amdgcn_mfma_f32_16x16x32_bf16(a, bz, aZ[t], 0, 0, 0);
      aH[t] = __builtin_amdgcn_mfma_f32_16x16x32_bf16(a, bn, aH[t], 0, 0, 0);
    }
  }

  // ---- epilogue: gates + state update (C/D: col=lane&15, row=g4*4+reg) ----
#pragma unroll
  for (int t = 0; t < 8; t++) {
    int col = t * 16 + m;
    float b_r = bih[col] + bhh[col];
    float b_z = bih[128 + col] + bhh[128 + col];
    float b_i = bih[256 + col];
    float b_h = bhh[256 + col];
#pragma unroll
    for (int r = 0; r < 4; r++) {
      int gr = rowBase + g4 * 4 + r;
      if (gr < N_NODES) {
        float rg = 1.f / (1.f + __expf(-(aR[t][r] + b_r)));
        float zg = 1.f / (1.f + __expf(-(aZ[t][r] + b_z)));
        float ng = tanhf(aN[t][r] + b_i + rg * (aH[t][r] + b_h));
        size_t o = (size_t)gr * 128 + col;
        float xo = x[o];
        float xn = (1.f - zg) * ng + zg * xo;
        x[o] = xn;
        xb[o] = (short)f2bf(xn);
      }
    }
  }
}

// ---------------------------------------------------------------------------
// BatchNorm (fp32 master x)
// ---------------------------------------------------------------------------
__global__ __launch_bounds__(256) void bn_stats(
    const float* __restrict__ x, float* __restrict__ sums)
{
  __shared__ float ls[256], lq[256];
  int tid  = threadIdx.x;
  int col  = tid & 127, half = tid >> 7;
  int r0   = blockIdx.x * 128;
  int rend = min(N_NODES, r0 + 128);
  float s = 0.f, q = 0.f;
  for (int r = r0 + half; r < rend; r += 2) {
    float v = x[(size_t)r * HDIM + col];
    s += v; q += v * v;
  }
  ls[tid] = s; lq[tid] = q;
  __syncthreads();
  if (tid < 128) {
    atomicAdd(&sums[col],       ls[tid] + ls[tid + 128]);
    atomicAdd(&sums[128 + col], lq[tid] + lq[tid + 128]);
  }
}

__global__ void bn_finalize(float* __restrict__ sums,
                            const float* __restrict__ gamma,
                            const float* __restrict__ beta)
{
  int j = threadIdx.x;
  float mean = sums[j] / (float)N_NODES;
  float var  = sums[128 + j] / (float)N_NODES - mean * mean;
  float inv  = rsqrtf(var + 1e-5f);
  sums[256 + j] = gamma[j] * inv;
  sums[384 + j] = beta[j] - mean * gamma[j] * inv;
}

__global__ __launch_bounds__(256) void bn_apply(
    float* __restrict__ x, const float* __restrict__ sums)
{
  int i = blockIdx.x * 256 + threadIdx.x;
  int j = i & 127;
  x[i] = x[i] * sums[256 + j] + sums[384 + j];
}

// ---------------------------------------------------------------------------
// Residual fold constants: E2 = embW @ mlpW  [128][40], c2 = mlpB + embB@mlpW
// ---------------------------------------------------------------------------
__global__ void prep_e2(const float* __restrict__ embW,
                        const float* __restrict__ embB,
                        const float* __restrict__ mlpW,
                        const float* __restrict__ mlpB,
                        float* __restrict__ e2, float* __restrict__ c2)
{
  int tid = threadIdx.x;
#pragma unroll
  for (int t = 0; t < 20; t++) {
    int idx = tid * 20 + t;
    int f = idx / 40, j = idx - f * 40;
    float s = 0.f;
    for (int k = 0; k < 128; k++)
      s = fmaf(embW[f * 128 + k], mlpW[k * 40 + j], s);
    e2[idx] = s;
  }
  if (tid < 40) {
    float s = mlpB[tid];
    for (int k = 0; k < 128; k++)
      s = fmaf(embB[k], mlpW[k * 40 + tid], s);
    c2[tid] = s;
  }
}

// ---------------------------------------------------------------------------
extern "C" void kernel_launch(void* const* d_in, const int* in_sizes, int n_in,
                              void* d_out, int out_size, void* d_ws, size_t ws_size,
                              hipStream_t stream)
{
  const float* h     = (const float*)d_in[0];
  const int*   ei    = (const int*)d_in[1];
  const float* ew    = (const float*)d_in[2];
  const float* embW  = (const float*)d_in[3];
  const float* embB  = (const float*)d_in[4];
  const float* convW = (const float*)d_in[5];   // [3][128][128]
  const float* Wih   = (const float*)d_in[6];   // [384][128]
  const float* Whh   = (const float*)d_in[7];   // [384][128]
  const float* bih   = (const float*)d_in[8];
  const float* bhh   = (const float*)d_in[9];
  const float* gamma = (const float*)d_in[10];
  const float* beta  = (const float*)d_in[11];
  const float* mlpW  = (const float*)d_in[12];
  const float* mlpB  = (const float*)d_in[13];
  float* out = (float*)d_out;

  float* ws = (float*)d_ws;
  const size_t NH = (size_t)N_NODES * HDIM;      // 12.8M
  float*    x      = ws;                          // [N][128] fp32 master
  unsigned* xbp    = (unsigned*)(ws + NH);        // [N][64] packed bf16
  unsigned* zbp    = xbp + NH / 2;                // [N][64] packed bf16
  int2*     epak   = (int2*)(zbp + NH / 2);       // [E] {src, w}
  int*      rowptr = (int*)(epak + N_EDGES);      // N+4
  int*      cnt    = rowptr + N_NODES + 4;        // N
  int*      deg    = cnt + N_NODES;               // N
  float*    Ffold  = (float*)(deg + N_NODES);     // [3][384][128] fp32
  unsigned* Fbp    = (unsigned*)(Ffold + 3 * 384 * 128);  // bf16 of Ffold
  unsigned* Wbp    = Fbp + 3 * 384 * 128 / 2;     // bf16 of Whh
  float*    sums   = (float*)(Wbp + 384 * 128 / 2);
  float*    e2     = sums + 512;
  float*    c2     = e2 + 5120;
  // total ~131 MB

  dim3 blk(256);
  const int MB = (N_NODES + 63) / 64;
  const int EB = (N_EDGES + 255) / 256;

  // ---- constants ----
  prep_e2<<<1, 256, 0, stream>>>(embW, embB, mlpW, mlpB, e2, c2);
  for (int l = 0; l < 3; l++)
    // Ffold_l[j][k] = sum_t Wih[j][t] * convW_l[k][t]   ([gate*128+col][k])
    gemm_k128<true, false><<<dim3(6, 1), blk, 0, stream>>>(
        Wih, convW + (size_t)l * HDIM * HDIM, nullptr,
        Ffold + (size_t)l * 384 * HDIM, 384, 128);
  f32_to_bf16_pack<<<(3 * 384 * 64 + 255) / 256, blk, 0, stream>>>(
      Ffold, Fbp, 3 * 384 * 64);
  f32_to_bf16_pack<<<(384 * 64 + 255) / 256, blk, 0, stream>>>(
      Whh, Wbp, 384 * 64);

  // ---- CSR build ----
  zero_i32<<<(2 * N_NODES + 255) / 256, blk, 0, stream>>>(cnt, 2 * N_NODES);
  csr_hist<<<EB, blk, 0, stream>>>(ei, deg);
  csr_scan<<<1, 1024, 0, stream>>>(deg, rowptr);
  csr_fill<<<EB, blk, 0, stream>>>(ei, ew, rowptr, cnt, epak);

  // ---- embedding: x = h @ embW + embB ; bf16 mirror ----
  gemm_k128<false, false><<<dim3(MB, 1), blk, 0, stream>>>(h, embW, embB, x, N_NODES, 128);
  f32_to_bf16_pack<<<(int)(NH / 2 + 255) / 256, blk, 0, stream>>>(x, xbp, (int)(NH / 2));

  // ---- 3 GRU layers: pull-agg (bf16) + fused MFMA GRU ----
  for (int l = 0; l < 3; l++) {
    agg_pull<<<(N_NODES + 3) / 4, blk, 0, stream>>>(xbp, rowptr, epak, zbp);
    gru_fused<<<MB, blk, 0, stream>>>(
        (const short*)zbp, (short*)xbp, x,
        (const short*)(Fbp) + (size_t)l * 384 * 128,
        (const short*)(Wbp), bih, bhh);
  }

  // ---- BatchNorm + residual-folded head ----
  zero_f32<<<2, blk, 0, stream>>>(sums, 512);
  bn_stats<<<(N_NODES + 127) / 128, blk, 0, stream>>>(x, sums);
  bn_finalize<<<1, 128, 0, stream>>>(sums, gamma, beta);
  bn_apply<<<(int)(NH / 256), blk, 0, stream>>>(x, sums);

  gemm_k128<false, false><<<dim3(MB, 1), blk, 0, stream>>>(x, mlpW, c2, out, N_NODES, 40);
  gemm_k128<false, true><<<dim3(MB, 1), blk, 0, stream>>>(h, e2, nullptr, out, N_NODES, 40);
}

// Round 5
// 1869.047 us; speedup vs baseline: 3.0478x; 1.1477x over previous
//
#include <hip/hip_runtime.h>
#include <math.h>

#define N_NODES 100000
#define N_EDGES 3200000
#define HDIM 128

typedef __attribute__((ext_vector_type(8))) short bf16x8;
typedef __attribute__((ext_vector_type(4))) float f32x4;

__device__ __forceinline__ unsigned short f2bf(float f) {
  union { float f; unsigned u; } v; v.f = f;
  unsigned r = v.u + 0x7fffu + ((v.u >> 16) & 1u);
  return (unsigned short)(r >> 16);
}
__device__ __forceinline__ float bflo(unsigned p) {
  union { unsigned u; float f; } v; v.u = p << 16; return v.f;
}
__device__ __forceinline__ float bfhi(unsigned p) {
  union { unsigned u; float f; } v; v.u = p & 0xffff0000u; return v.f;
}

// ---------------------------------------------------------------------------
__global__ __launch_bounds__(256) void zero_i32(int* __restrict__ p, int n) {
  int i = blockIdx.x * 256 + threadIdx.x;
  if (i < n) p[i] = 0;
}
__global__ __launch_bounds__(256) void zero_f32(float* __restrict__ p, int n) {
  int i = blockIdx.x * 256 + threadIdx.x;
  if (i < n) p[i] = 0.f;
}
// pack 2 consecutive floats -> 2 bf16 in one u32
__global__ __launch_bounds__(256) void f32_to_bf16_pack(
    const float* __restrict__ src, unsigned* __restrict__ dst, int n2) {
  int i = blockIdx.x * 256 + threadIdx.x;
  if (i >= n2) return;
  dst[i] = (unsigned)f2bf(src[2 * i]) | ((unsigned)f2bf(src[2 * i + 1]) << 16);
}

// ---------------------------------------------------------------------------
// Repack a [384][128] fp32 weight matrix (row-major [col][k]) into
// MFMA-B-fragment-ordered bf16: dst[((t*4+ks)*64 + lane)*8 + j] =
// bf16(src[(t*16 + (lane&15))*128 + ks*32 + (lane>>4)*8 + j]).
// After this, a wave's B-frag load is lane*16B contiguous (1 KB/instr).
// ---------------------------------------------------------------------------
__global__ __launch_bounds__(256) void repack_frag_b(
    const float* __restrict__ src, short* __restrict__ dst)
{
  int o = blockIdx.x * 256 + threadIdx.x;      // 0 .. 384*128-1
  if (o >= 384 * 128) return;
  int j    = o & 7;
  int lane = (o >> 3) & 63;
  int ks   = (o >> 9) & 3;
  int t    = o >> 11;
  int m  = lane & 15;
  int g4 = lane >> 4;
  dst[o] = (short)f2bf(src[(t * 16 + m) * 128 + ks * 32 + g4 * 8 + j]);
}

// ---------------------------------------------------------------------------
// Tiled fp32 GEMM, K fixed at 128 (emb, head, weight folds).
// ---------------------------------------------------------------------------
template<bool BT, bool ACC>
__global__ __launch_bounds__(256) void gemm_k128(
    const float* __restrict__ A, const float* __restrict__ W,
    const float* __restrict__ bias, float* __restrict__ Y,
    int M, int OUT)
{
  __shared__ alignas(16) float lds_a[32 * 68];
  __shared__ alignas(16) float lds_b[32 * 132];
  const int tid = threadIdx.x;
  const int tx = tid & 15;
  const int ty = tid >> 4;
  const int rowBase = blockIdx.x * 64;
  const int colBase = blockIdx.y * 128;

  float acc[4][8];
#pragma unroll
  for (int r = 0; r < 4; r++)
#pragma unroll
    for (int c = 0; c < 8; c++) acc[r][c] = 0.f;

  for (int k0 = 0; k0 < 128; k0 += 32) {
#pragma unroll
    for (int i = 0; i < 2; i++) {
      int idx = tid + i * 256;
      int r   = idx >> 3;
      int kk  = (idx & 7) << 2;
      int gr  = rowBase + r;
      float4 v = make_float4(0.f, 0.f, 0.f, 0.f);
      if (gr < M) v = *(const float4*)(A + (size_t)gr * HDIM + k0 + kk);
      lds_a[(kk + 0) * 68 + r] = v.x;
      lds_a[(kk + 1) * 68 + r] = v.y;
      lds_a[(kk + 2) * 68 + r] = v.z;
      lds_a[(kk + 3) * 68 + r] = v.w;
    }
    if (!BT) {
#pragma unroll
      for (int i = 0; i < 4; i++) {
        int idx = tid + i * 256;
        int kk  = idx >> 5;
        int j   = (idx & 31) << 2;
        int gj  = colBase + j;
        float4 v = make_float4(0.f, 0.f, 0.f, 0.f);
        if (gj < OUT) v = *(const float4*)(W + (size_t)(k0 + kk) * OUT + gj);
        *((float4*)&lds_b[kk * 132 + j]) = v;
      }
    } else {
#pragma unroll
      for (int i = 0; i < 4; i++) {
        int idx = tid + i * 256;
        int j   = idx >> 3;
        int k4  = (idx & 7) << 2;
        int gj  = colBase + j;
        float4 v = make_float4(0.f, 0.f, 0.f, 0.f);
        if (gj < OUT) v = *(const float4*)(W + (size_t)gj * HDIM + k0 + k4);
        lds_b[(k4 + 0) * 132 + j] = v.x;
        lds_b[(k4 + 1) * 132 + j] = v.y;
        lds_b[(k4 + 2) * 132 + j] = v.z;
        lds_b[(k4 + 3) * 132 + j] = v.w;
      }
    }
    __syncthreads();
#pragma unroll 8
    for (int kk = 0; kk < 32; kk++) {
      float4 a4 = *(const float4*)&lds_a[kk * 68 + ty * 4];
      float4 b0 = *(const float4*)&lds_b[kk * 132 + tx * 8];
      float4 b1 = *(const float4*)&lds_b[kk * 132 + tx * 8 + 4];
      float av[4] = {a4.x, a4.y, a4.z, a4.w};
      float bv[8] = {b0.x, b0.y, b0.z, b0.w, b1.x, b1.y, b1.z, b1.w};
#pragma unroll
      for (int r = 0; r < 4; r++)
#pragma unroll
        for (int c = 0; c < 8; c++)
          acc[r][c] = fmaf(av[r], bv[c], acc[r][c]);
    }
    __syncthreads();
  }

  int col = colBase + tx * 8;
  if (col >= OUT) return;
  float bv[8];
#pragma unroll
  for (int c = 0; c < 8; c++) bv[c] = bias ? bias[col + c] : 0.f;
#pragma unroll
  for (int r = 0; r < 4; r++) {
    int gr = rowBase + ty * 4 + r;
    if (gr >= M) continue;
    float* yp = Y + (size_t)gr * OUT + col;
    float4 o0 = make_float4(acc[r][0] + bv[0], acc[r][1] + bv[1],
                            acc[r][2] + bv[2], acc[r][3] + bv[3]);
    float4 o1 = make_float4(acc[r][4] + bv[4], acc[r][5] + bv[5],
                            acc[r][6] + bv[6], acc[r][7] + bv[7]);
    if (ACC) {
      float4 y0 = *(float4*)yp;
      float4 y1 = *(float4*)(yp + 4);
      o0.x += y0.x; o0.y += y0.y; o0.z += y0.z; o0.w += y0.w;
      o1.x += y1.x; o1.y += y1.y; o1.z += y1.z; o1.w += y1.w;
    }
    *(float4*)yp       = o0;
    *(float4*)(yp + 4) = o1;
  }
}

// ---------------------------------------------------------------------------
// CSR build (by destination), edges packed as int2{src, w_bits}.
// ---------------------------------------------------------------------------
__global__ __launch_bounds__(256) void csr_hist(
    const int* __restrict__ ei, int* __restrict__ deg)
{
  int e = blockIdx.x * 256 + threadIdx.x;
  if (e < N_EDGES) atomicAdd(&deg[ei[N_EDGES + e]], 1);
}

__global__ __launch_bounds__(1024) void csr_scan(
    const int* __restrict__ deg, int* __restrict__ rowptr)
{
  __shared__ int lds[1024];
  __shared__ int s_carry;
  int tid = threadIdx.x;
  if (tid == 0) s_carry = 0;
  __syncthreads();
  for (int base = 0; base < N_NODES; base += 1024) {
    int i = base + tid;
    int v = (i < N_NODES) ? deg[i] : 0;
    lds[tid] = v;
    __syncthreads();
    for (int off = 1; off < 1024; off <<= 1) {
      int t = (tid >= off) ? lds[tid - off] : 0;
      __syncthreads();
      lds[tid] += t;
      __syncthreads();
    }
    int carry = s_carry;
    if (i < N_NODES) rowptr[i] = carry + lds[tid] - v;
    __syncthreads();
    if (tid == 1023) s_carry = carry + lds[1023];
    __syncthreads();
  }
  if (tid == 0) rowptr[N_NODES] = s_carry;
}

__global__ __launch_bounds__(256) void csr_fill(
    const int* __restrict__ ei, const float* __restrict__ ew,
    const int* __restrict__ rowptr, int* __restrict__ cnt,
    int2* __restrict__ epak)
{
  int e = blockIdx.x * 256 + threadIdx.x;
  if (e >= N_EDGES) return;
  int d = ei[N_EDGES + e];
  int pos = rowptr[d] + atomicAdd(&cnt[d], 1);
  epak[pos] = make_int2(ei[e], __float_as_int(ew[e]));
}

// ---------------------------------------------------------------------------
// Pull aggregation on bf16 x: z[n] = sum w_e * x[src_e], fp32 accumulate,
// bf16 packed output. One wave/node, lane covers cols {2*lane, 2*lane+1}.
// ---------------------------------------------------------------------------
__global__ __launch_bounds__(256) void agg_pull(
    const unsigned* __restrict__ xbp, const int* __restrict__ rowptr,
    const int2* __restrict__ epak, unsigned* __restrict__ zbp)
{
  int node = blockIdx.x * 4 + (threadIdx.x >> 6);
  if (node >= N_NODES) return;
  int lane = threadIdx.x & 63;
  int s0 = rowptr[node], s1 = rowptr[node + 1];
  float v0 = 0.f, v1 = 0.f;
  int e = s0;
  for (; e + 3 < s1; e += 4) {
    int2 e0 = epak[e], e1 = epak[e + 1], e2 = epak[e + 2], e3 = epak[e + 3];
    unsigned p0 = xbp[(size_t)e0.x * 64 + lane];
    unsigned p1 = xbp[(size_t)e1.x * 64 + lane];
    unsigned p2 = xbp[(size_t)e2.x * 64 + lane];
    unsigned p3 = xbp[(size_t)e3.x * 64 + lane];
    float w0 = __int_as_float(e0.y), w1 = __int_as_float(e1.y);
    float w2 = __int_as_float(e2.y), w3 = __int_as_float(e3.y);
    v0 = fmaf(w0, bflo(p0), v0); v1 = fmaf(w0, bfhi(p0), v1);
    v0 = fmaf(w1, bflo(p1), v0); v1 = fmaf(w1, bfhi(p1), v1);
    v0 = fmaf(w2, bflo(p2), v0); v1 = fmaf(w2, bfhi(p2), v1);
    v0 = fmaf(w3, bflo(p3), v0); v1 = fmaf(w3, bfhi(p3), v1);
  }
  for (; e < s1; e++) {
    int2 ep = epak[e];
    unsigned p = xbp[(size_t)ep.x * 64 + lane];
    float w = __int_as_float(ep.y);
    v0 = fmaf(w, bflo(p), v0); v1 = fmaf(w, bfhi(p), v1);
  }
  zbp[(size_t)node * 64 + lane] =
      (unsigned)f2bf(v0) | ((unsigned)f2bf(v1) << 16);
}

// ---------------------------------------------------------------------------
// Fused GRU layer (bf16 MFMA): per wave 16 rows x 128 gate-cols.
// B matrices (Fb, Wb) are pre-repacked in fragment order: the per-(t,ks)
// fragment block is 64 lanes x 16 B contiguous -> fully coalesced loads.
// ---------------------------------------------------------------------------
__global__ __launch_bounds__(256) void gru_fused(
    const short* __restrict__ zb, short* __restrict__ xb,
    float* __restrict__ x,
    const short* __restrict__ Fb, const short* __restrict__ Wb,
    const float* __restrict__ bih, const float* __restrict__ bhh)
{
  const int wave = threadIdx.x >> 6, lane = threadIdx.x & 63;
  const int m  = lane & 15;          // A row / C col within tile
  const int g4 = lane >> 4;          // k-group
  const int rowBase = blockIdx.x * 64 + wave * 16;
  int arow = rowBase + m;
  int arowc = arow < N_NODES ? arow : N_NODES - 1;

  f32x4 aR[8], aZ[8], aN[8], aH[8];
#pragma unroll
  for (int t = 0; t < 8; t++) {
    aR[t] = (f32x4){0.f, 0.f, 0.f, 0.f};
    aZ[t] = (f32x4){0.f, 0.f, 0.f, 0.f};
    aN[t] = (f32x4){0.f, 0.f, 0.f, 0.f};
    aH[t] = (f32x4){0.f, 0.f, 0.f, 0.f};
  }

  const short* az = zb + (size_t)arowc * 128 + g4 * 8;
  const short* ax = xb + (size_t)arowc * 128 + g4 * 8;
  const int laneOff = lane * 8;      // fragment-order B: contiguous per lane

  // ---- phase 0: z @ F  -> r,z,i_n ----
#pragma unroll
  for (int ks = 0; ks < 4; ks++) {
    bf16x8 a = *(const bf16x8*)(az + ks * 32);
    int bo = ks * 512 + laneOff;
#pragma unroll
    for (int t = 0; t < 8; t++) {
      const short* bp = Fb + t * 2048 + bo;
      bf16x8 br = *(const bf16x8*)(bp);
      bf16x8 bz = *(const bf16x8*)(bp + 16384);
      bf16x8 bn = *(const bf16x8*)(bp + 32768);
      aR[t] = __builtin_amdgcn_mfma_f32_16x16x32_bf16(a, br, aR[t], 0, 0, 0);
      aZ[t] = __builtin_amdgcn_mfma_f32_16x16x32_bf16(a, bz, aZ[t], 0, 0, 0);
      aN[t] = __builtin_amdgcn_mfma_f32_16x16x32_bf16(a, bn, aN[t], 0, 0, 0);
    }
  }
  // ---- phase 1: x @ Whh^T -> r,z,h_n ----
#pragma unroll
  for (int ks = 0; ks < 4; ks++) {
    bf16x8 a = *(const bf16x8*)(ax + ks * 32);
    int bo = ks * 512 + laneOff;
#pragma unroll
    for (int t = 0; t < 8; t++) {
      const short* bp = Wb + t * 2048 + bo;
      bf16x8 br = *(const bf16x8*)(bp);
      bf16x8 bz = *(const bf16x8*)(bp + 16384);
      bf16x8 bn = *(const bf16x8*)(bp + 32768);
      aR[t] = __builtin_amdgcn_mfma_f32_16x16x32_bf16(a, br, aR[t], 0, 0, 0);
      aZ[t] = __builtin_amdgcn_mfma_f32_16x16x32_bf16(a, bz, aZ[t], 0, 0, 0);
      aH[t] = __builtin_amdgcn_mfma_f32_16x16x32_bf16(a, bn, aH[t], 0, 0, 0);
    }
  }

  // ---- epilogue: gates + state update (C/D: col=lane&15, row=g4*4+reg) ----
#pragma unroll
  for (int t = 0; t < 8; t++) {
    int col = t * 16 + m;
    float b_r = bih[col] + bhh[col];
    float b_z = bih[128 + col] + bhh[128 + col];
    float b_i = bih[256 + col];
    float b_h = bhh[256 + col];
#pragma unroll
    for (int r = 0; r < 4; r++) {
      int gr = rowBase + g4 * 4 + r;
      if (gr < N_NODES) {
        float rg = 1.f / (1.f + __expf(-(aR[t][r] + b_r)));
        float zg = 1.f / (1.f + __expf(-(aZ[t][r] + b_z)));
        float ng = tanhf(aN[t][r] + b_i + rg * (aH[t][r] + b_h));
        size_t o = (size_t)gr * 128 + col;
        float xo = x[o];
        float xn = (1.f - zg) * ng + zg * xo;
        x[o] = xn;
        xb[o] = (short)f2bf(xn);
      }
    }
  }
}

// ---------------------------------------------------------------------------
// BatchNorm (fp32 master x)
// ---------------------------------------------------------------------------
__global__ __launch_bounds__(256) void bn_stats(
    const float* __restrict__ x, float* __restrict__ sums)
{
  __shared__ float ls[256], lq[256];
  int tid  = threadIdx.x;
  int col  = tid & 127, half = tid >> 7;
  int r0   = blockIdx.x * 128;
  int rend = min(N_NODES, r0 + 128);
  float s = 0.f, q = 0.f;
  for (int r = r0 + half; r < rend; r += 2) {
    float v = x[(size_t)r * HDIM + col];
    s += v; q += v * v;
  }
  ls[tid] = s; lq[tid] = q;
  __syncthreads();
  if (tid < 128) {
    atomicAdd(&sums[col],       ls[tid] + ls[tid + 128]);
    atomicAdd(&sums[128 + col], lq[tid] + lq[tid + 128]);
  }
}

__global__ void bn_finalize(float* __restrict__ sums,
                            const float* __restrict__ gamma,
                            const float* __restrict__ beta)
{
  int j = threadIdx.x;
  float mean = sums[j] / (float)N_NODES;
  float var  = sums[128 + j] / (float)N_NODES - mean * mean;
  float inv  = rsqrtf(var + 1e-5f);
  sums[256 + j] = gamma[j] * inv;
  sums[384 + j] = beta[j] - mean * gamma[j] * inv;
}

__global__ __launch_bounds__(256) void bn_apply(
    float* __restrict__ x, const float* __restrict__ sums)
{
  int i = blockIdx.x * 256 + threadIdx.x;
  int j = i & 127;
  x[i] = x[i] * sums[256 + j] + sums[384 + j];
}

// ---------------------------------------------------------------------------
// Residual fold constants: E2 = embW @ mlpW  [128][40], c2 = mlpB + embB@mlpW
// ---------------------------------------------------------------------------
__global__ void prep_e2(const float* __restrict__ embW,
                        const float* __restrict__ embB,
                        const float* __restrict__ mlpW,
                        const float* __restrict__ mlpB,
                        float* __restrict__ e2, float* __restrict__ c2)
{
  int tid = threadIdx.x;
#pragma unroll
  for (int t = 0; t < 20; t++) {
    int idx = tid * 20 + t;
    int f = idx / 40, j = idx - f * 40;
    float s = 0.f;
    for (int k = 0; k < 128; k++)
      s = fmaf(embW[f * 128 + k], mlpW[k * 40 + j], s);
    e2[idx] = s;
  }
  if (tid < 40) {
    float s = mlpB[tid];
    for (int k = 0; k < 128; k++)
      s = fmaf(embB[k], mlpW[k * 40 + tid], s);
    c2[tid] = s;
  }
}

// ---------------------------------------------------------------------------
extern "C" void kernel_launch(void* const* d_in, const int* in_sizes, int n_in,
                              void* d_out, int out_size, void* d_ws, size_t ws_size,
                              hipStream_t stream)
{
  const float* h     = (const float*)d_in[0];
  const int*   ei    = (const int*)d_in[1];
  const float* ew    = (const float*)d_in[2];
  const float* embW  = (const float*)d_in[3];
  const float* embB  = (const float*)d_in[4];
  const float* convW = (const float*)d_in[5];   // [3][128][128]
  const float* Wih   = (const float*)d_in[6];   // [384][128]
  const float* Whh   = (const float*)d_in[7];   // [384][128]
  const float* bih   = (const float*)d_in[8];
  const float* bhh   = (const float*)d_in[9];
  const float* gamma = (const float*)d_in[10];
  const float* beta  = (const float*)d_in[11];
  const float* mlpW  = (const float*)d_in[12];
  const float* mlpB  = (const float*)d_in[13];
  float* out = (float*)d_out;

  float* ws = (float*)d_ws;
  const size_t NH = (size_t)N_NODES * HDIM;      // 12.8M
  float*    x      = ws;                          // [N][128] fp32 master
  unsigned* xbp    = (unsigned*)(ws + NH);        // [N][64] packed bf16
  unsigned* zbp    = xbp + NH / 2;                // [N][64] packed bf16
  int2*     epak   = (int2*)(zbp + NH / 2);       // [E] {src, w}
  int*      rowptr = (int*)(epak + N_EDGES);      // N+4
  int*      cnt    = rowptr + N_NODES + 4;        // N
  int*      deg    = cnt + N_NODES;               // N
  float*    Ffold  = (float*)(deg + N_NODES);     // [3][384][128] fp32
  short*    Fbp    = (short*)(Ffold + 3 * 384 * 128);  // frag-order bf16
  short*    Wbp    = Fbp + 3 * 384 * 128;         // frag-order bf16 of Whh
  float*    sums   = (float*)(Wbp + 384 * 128);
  float*    e2     = sums + 512;
  float*    c2     = e2 + 5120;
  // total ~131 MB

  dim3 blk(256);
  const int MB = (N_NODES + 63) / 64;
  const int EB = (N_EDGES + 255) / 256;
  const int RB = (384 * 128 + 255) / 256;         // repack blocks

  // ---- constants ----
  prep_e2<<<1, 256, 0, stream>>>(embW, embB, mlpW, mlpB, e2, c2);
  for (int l = 0; l < 3; l++)
    // Ffold_l[j][k] = sum_t Wih[j][t] * convW_l[k][t]   ([gate*128+col][k])
    gemm_k128<true, false><<<dim3(6, 1), blk, 0, stream>>>(
        Wih, convW + (size_t)l * HDIM * HDIM, nullptr,
        Ffold + (size_t)l * 384 * HDIM, 384, 128);
  for (int l = 0; l < 3; l++)
    repack_frag_b<<<RB, blk, 0, stream>>>(
        Ffold + (size_t)l * 384 * HDIM, Fbp + (size_t)l * 384 * HDIM);
  repack_frag_b<<<RB, blk, 0, stream>>>(Whh, Wbp);

  // ---- CSR build ----
  zero_i32<<<(2 * N_NODES + 255) / 256, blk, 0, stream>>>(cnt, 2 * N_NODES);
  csr_hist<<<EB, blk, 0, stream>>>(ei, deg);
  csr_scan<<<1, 1024, 0, stream>>>(deg, rowptr);
  csr_fill<<<EB, blk, 0, stream>>>(ei, ew, rowptr, cnt, epak);

  // ---- embedding: x = h @ embW + embB ; bf16 mirror ----
  gemm_k128<false, false><<<dim3(MB, 1), blk, 0, stream>>>(h, embW, embB, x, N_NODES, 128);
  f32_to_bf16_pack<<<(int)(NH / 2 + 255) / 256, blk, 0, stream>>>(x, xbp, (int)(NH / 2));

  // ---- 3 GRU layers: pull-agg (bf16) + fused MFMA GRU ----
  for (int l = 0; l < 3; l++) {
    agg_pull<<<(N_NODES + 3) / 4, blk, 0, stream>>>(xbp, rowptr, epak, zbp);
    gru_fused<<<MB, blk, 0, stream>>>(
        (const short*)zbp, (short*)xbp, x,
        Fbp + (size_t)l * 384 * HDIM, Wbp, bih, bhh);
  }

  // ---- BatchNorm + residual-folded head ----
  zero_f32<<<2, blk, 0, stream>>>(sums, 512);
  bn_stats<<<(N_NODES + 127) / 128, blk, 0, stream>>>(x, sums);
  bn_finalize<<<1, 128, 0, stream>>>(sums, gamma, beta);
  bn_apply<<<(int)(NH / 256), blk, 0, stream>>>(x, sums);

  gemm_k128<false, false><<<dim3(MB, 1), blk, 0, stream>>>(x, mlpW, c2, out, N_NODES, 40);
  gemm_k128<false, true><<<dim3(MB, 1), blk, 0, stream>>>(h, e2, nullptr, out, N_NODES, 40);
}

// Round 6
// 1708.420 us; speedup vs baseline: 3.3344x; 1.0940x over previous
//
#include <hip/hip_runtime.h>
#include <math.h>

#define N_NODES 100000
#define N_EDGES 3200000
#define HDIM 128

typedef __attribute__((ext_vector_type(8))) short bf16x8;
typedef __attribute__((ext_vector_type(4))) float f32x4;

__device__ __forceinline__ unsigned short f2bf(float f) {
  union { float f; unsigned u; } v; v.f = f;
  unsigned r = v.u + 0x7fffu + ((v.u >> 16) & 1u);
  return (unsigned short)(r >> 16);
}
__device__ __forceinline__ float bflo(unsigned p) {
  union { unsigned u; float f; } v; v.u = p << 16; return v.f;
}
__device__ __forceinline__ float bfhi(unsigned p) {
  union { unsigned u; float f; } v; v.u = p & 0xffff0000u; return v.f;
}

// ---------------------------------------------------------------------------
__global__ __launch_bounds__(256) void zero_i32(int* __restrict__ p, int n) {
  int i = blockIdx.x * 256 + threadIdx.x;
  if (i < n) p[i] = 0;
}
__global__ __launch_bounds__(256) void zero_f32(float* __restrict__ p, int n) {
  int i = blockIdx.x * 256 + threadIdx.x;
  if (i < n) p[i] = 0.f;
}
// pack 2 consecutive floats -> 2 bf16 in one u32
__global__ __launch_bounds__(256) void f32_to_bf16_pack(
    const float* __restrict__ src, unsigned* __restrict__ dst, int n2) {
  int i = blockIdx.x * 256 + threadIdx.x;
  if (i >= n2) return;
  dst[i] = (unsigned)f2bf(src[2 * i]) | ((unsigned)f2bf(src[2 * i + 1]) << 16);
}

// ---------------------------------------------------------------------------
// Repack a [384][128] fp32 weight matrix (row-major [col][k]) into
// MFMA-B-fragment-ordered bf16 (lane*16B contiguous per fragment).
// ---------------------------------------------------------------------------
__global__ __launch_bounds__(256) void repack_frag_b(
    const float* __restrict__ src, short* __restrict__ dst)
{
  int o = blockIdx.x * 256 + threadIdx.x;      // 0 .. 384*128-1
  if (o >= 384 * 128) return;
  int j    = o & 7;
  int lane = (o >> 3) & 63;
  int ks   = (o >> 9) & 3;
  int t    = o >> 11;
  int m  = lane & 15;
  int g4 = lane >> 4;
  dst[o] = (short)f2bf(src[(t * 16 + m) * 128 + ks * 32 + g4 * 8 + j]);
}

// ---------------------------------------------------------------------------
// Tiled fp32 GEMM, K fixed at 128 (emb, head, weight folds).
// ---------------------------------------------------------------------------
template<bool BT, bool ACC>
__global__ __launch_bounds__(256) void gemm_k128(
    const float* __restrict__ A, const float* __restrict__ W,
    const float* __restrict__ bias, float* __restrict__ Y,
    int M, int OUT)
{
  __shared__ alignas(16) float lds_a[32 * 68];
  __shared__ alignas(16) float lds_b[32 * 132];
  const int tid = threadIdx.x;
  const int tx = tid & 15;
  const int ty = tid >> 4;
  const int rowBase = blockIdx.x * 64;
  const int colBase = blockIdx.y * 128;

  float acc[4][8];
#pragma unroll
  for (int r = 0; r < 4; r++)
#pragma unroll
    for (int c = 0; c < 8; c++) acc[r][c] = 0.f;

  for (int k0 = 0; k0 < 128; k0 += 32) {
#pragma unroll
    for (int i = 0; i < 2; i++) {
      int idx = tid + i * 256;
      int r   = idx >> 3;
      int kk  = (idx & 7) << 2;
      int gr  = rowBase + r;
      float4 v = make_float4(0.f, 0.f, 0.f, 0.f);
      if (gr < M) v = *(const float4*)(A + (size_t)gr * HDIM + k0 + kk);
      lds_a[(kk + 0) * 68 + r] = v.x;
      lds_a[(kk + 1) * 68 + r] = v.y;
      lds_a[(kk + 2) * 68 + r] = v.z;
      lds_a[(kk + 3) * 68 + r] = v.w;
    }
    if (!BT) {
#pragma unroll
      for (int i = 0; i < 4; i++) {
        int idx = tid + i * 256;
        int kk  = idx >> 5;
        int j   = (idx & 31) << 2;
        int gj  = colBase + j;
        float4 v = make_float4(0.f, 0.f, 0.f, 0.f);
        if (gj < OUT) v = *(const float4*)(W + (size_t)(k0 + kk) * OUT + gj);
        *((float4*)&lds_b[kk * 132 + j]) = v;
      }
    } else {
#pragma unroll
      for (int i = 0; i < 4; i++) {
        int idx = tid + i * 256;
        int j   = idx >> 3;
        int k4  = (idx & 7) << 2;
        int gj  = colBase + j;
        float4 v = make_float4(0.f, 0.f, 0.f, 0.f);
        if (gj < OUT) v = *(const float4*)(W + (size_t)gj * HDIM + k0 + k4);
        lds_b[(k4 + 0) * 132 + j] = v.x;
        lds_b[(k4 + 1) * 132 + j] = v.y;
        lds_b[(k4 + 2) * 132 + j] = v.z;
        lds_b[(k4 + 3) * 132 + j] = v.w;
      }
    }
    __syncthreads();
#pragma unroll 8
    for (int kk = 0; kk < 32; kk++) {
      float4 a4 = *(const float4*)&lds_a[kk * 68 + ty * 4];
      float4 b0 = *(const float4*)&lds_b[kk * 132 + tx * 8];
      float4 b1 = *(const float4*)&lds_b[kk * 132 + tx * 8 + 4];
      float av[4] = {a4.x, a4.y, a4.z, a4.w};
      float bv[8] = {b0.x, b0.y, b0.z, b0.w, b1.x, b1.y, b1.z, b1.w};
#pragma unroll
      for (int r = 0; r < 4; r++)
#pragma unroll
        for (int c = 0; c < 8; c++)
          acc[r][c] = fmaf(av[r], bv[c], acc[r][c]);
    }
    __syncthreads();
  }

  int col = colBase + tx * 8;
  if (col >= OUT) return;
  float bv[8];
#pragma unroll
  for (int c = 0; c < 8; c++) bv[c] = bias ? bias[col + c] : 0.f;
#pragma unroll
  for (int r = 0; r < 4; r++) {
    int gr = rowBase + ty * 4 + r;
    if (gr >= M) continue;
    float* yp = Y + (size_t)gr * OUT + col;
    float4 o0 = make_float4(acc[r][0] + bv[0], acc[r][1] + bv[1],
                            acc[r][2] + bv[2], acc[r][3] + bv[3]);
    float4 o1 = make_float4(acc[r][4] + bv[4], acc[r][5] + bv[5],
                            acc[r][6] + bv[6], acc[r][7] + bv[7]);
    if (ACC) {
      float4 y0 = *(float4*)yp;
      float4 y1 = *(float4*)(yp + 4);
      o0.x += y0.x; o0.y += y0.y; o0.z += y0.z; o0.w += y0.w;
      o1.x += y1.x; o1.y += y1.y; o1.z += y1.z; o1.w += y1.w;
    }
    *(float4*)yp       = o0;
    *(float4*)(yp + 4) = o1;
  }
}

// ---------------------------------------------------------------------------
// CSR build (by destination), edges packed as int2{src, w_bits}.
// ---------------------------------------------------------------------------
__global__ __launch_bounds__(256) void csr_hist(
    const int* __restrict__ ei, int* __restrict__ deg)
{
  int e = blockIdx.x * 256 + threadIdx.x;
  if (e < N_EDGES) atomicAdd(&deg[ei[N_EDGES + e]], 1);
}

// ---- hierarchical exclusive scan of deg[N] -> rowptr[N+1] ----
// stage 1: 2048 elems/block (8/thread), per-block exclusive scan + block total
__global__ __launch_bounds__(256) void scan_blk(
    const int* __restrict__ deg, int* __restrict__ rowptr,
    int* __restrict__ blksum)
{
  __shared__ int lds[256];
  int tid  = threadIdx.x;
  int idx0 = blockIdx.x * 2048 + tid * 8;
  int v[8];
  int local = 0;
#pragma unroll
  for (int j = 0; j < 8; j++) {
    int i = idx0 + j;
    v[j] = (i < N_NODES) ? deg[i] : 0;
    local += v[j];
  }
  lds[tid] = local;
  __syncthreads();
  int inc = local;
  for (int off = 1; off < 256; off <<= 1) {
    int t = (tid >= off) ? lds[tid - off] : 0;
    __syncthreads();
    lds[tid] += t;
    __syncthreads();
  }
  int run = lds[tid] - inc;          // exclusive prefix within block
#pragma unroll
  for (int j = 0; j < 8; j++) {
    int i = idx0 + j;
    if (i < N_NODES) rowptr[i] = run;
    run += v[j];
  }
  if (tid == 255) blksum[blockIdx.x] = lds[255];
}

// stage 2: one wave scans <=64 block totals (exclusive); writes rowptr[N]
__global__ void scan_top(int* __restrict__ blksum, int nblk,
                         int* __restrict__ rowptr)
{
  int tid = threadIdx.x;             // 64 threads
  int orig = (tid < nblk) ? blksum[tid] : 0;
  int v = orig;
  for (int off = 1; off < 64; off <<= 1) {
    int t = __shfl_up(v, off, 64);
    if (tid >= off) v += t;
  }
  if (tid < nblk) blksum[tid] = v - orig;   // exclusive
  if (tid == 63) rowptr[N_NODES] = v;       // total == E
}

// stage 3: add block offsets
__global__ __launch_bounds__(256) void scan_add(
    int* __restrict__ rowptr, const int* __restrict__ blksum)
{
  int i = blockIdx.x * 256 + threadIdx.x;
  if (i < N_NODES) rowptr[i] += blksum[i >> 11];
}

__global__ __launch_bounds__(256) void csr_fill(
    const int* __restrict__ ei, const float* __restrict__ ew,
    const int* __restrict__ rowptr, int* __restrict__ cnt,
    int2* __restrict__ epak)
{
  int e = blockIdx.x * 256 + threadIdx.x;
  if (e >= N_EDGES) return;
  int d = ei[N_EDGES + e];
  int pos = rowptr[d] + atomicAdd(&cnt[d], 1);
  epak[pos] = make_int2(ei[e], __float_as_int(ew[e]));
}

// ---------------------------------------------------------------------------
// Pull aggregation on bf16 x: z[n] = sum w_e * x[src_e], fp32 accumulate,
// bf16 packed output. One wave/node, lane covers cols {2*lane, 2*lane+1}.
// ---------------------------------------------------------------------------
__global__ __launch_bounds__(256) void agg_pull(
    const unsigned* __restrict__ xbp, const int* __restrict__ rowptr,
    const int2* __restrict__ epak, unsigned* __restrict__ zbp)
{
  int node = blockIdx.x * 4 + (threadIdx.x >> 6);
  if (node >= N_NODES) return;
  int lane = threadIdx.x & 63;
  int s0 = rowptr[node], s1 = rowptr[node + 1];
  float v0 = 0.f, v1 = 0.f;
  int e = s0;
  for (; e + 3 < s1; e += 4) {
    int2 e0 = epak[e], e1 = epak[e + 1], e2 = epak[e + 2], e3 = epak[e + 3];
    unsigned p0 = xbp[(size_t)e0.x * 64 + lane];
    unsigned p1 = xbp[(size_t)e1.x * 64 + lane];
    unsigned p2 = xbp[(size_t)e2.x * 64 + lane];
    unsigned p3 = xbp[(size_t)e3.x * 64 + lane];
    float w0 = __int_as_float(e0.y), w1 = __int_as_float(e1.y);
    float w2 = __int_as_float(e2.y), w3 = __int_as_float(e3.y);
    v0 = fmaf(w0, bflo(p0), v0); v1 = fmaf(w0, bfhi(p0), v1);
    v0 = fmaf(w1, bflo(p1), v0); v1 = fmaf(w1, bfhi(p1), v1);
    v0 = fmaf(w2, bflo(p2), v0); v1 = fmaf(w2, bfhi(p2), v1);
    v0 = fmaf(w3, bflo(p3), v0); v1 = fmaf(w3, bfhi(p3), v1);
  }
  for (; e < s1; e++) {
    int2 ep = epak[e];
    unsigned p = xbp[(size_t)ep.x * 64 + lane];
    float w = __int_as_float(ep.y);
    v0 = fmaf(w, bflo(p), v0); v1 = fmaf(w, bfhi(p), v1);
  }
  zbp[(size_t)node * 64 + lane] =
      (unsigned)f2bf(v0) | ((unsigned)f2bf(v1) << 16);
}

// ---------------------------------------------------------------------------
// Fused GRU layer (bf16 MFMA): per wave 16 rows x 128 gate-cols.
// B matrices pre-repacked in fragment order (coalesced lane*16B loads).
// ---------------------------------------------------------------------------
__global__ __launch_bounds__(256) void gru_fused(
    const short* __restrict__ zb, short* __restrict__ xb,
    float* __restrict__ x,
    const short* __restrict__ Fb, const short* __restrict__ Wb,
    const float* __restrict__ bih, const float* __restrict__ bhh)
{
  const int wave = threadIdx.x >> 6, lane = threadIdx.x & 63;
  const int m  = lane & 15;
  const int g4 = lane >> 4;
  const int rowBase = blockIdx.x * 64 + wave * 16;
  int arow = rowBase + m;
  int arowc = arow < N_NODES ? arow : N_NODES - 1;

  f32x4 aR[8], aZ[8], aN[8], aH[8];
#pragma unroll
  for (int t = 0; t < 8; t++) {
    aR[t] = (f32x4){0.f, 0.f, 0.f, 0.f};
    aZ[t] = (f32x4){0.f, 0.f, 0.f, 0.f};
    aN[t] = (f32x4){0.f, 0.f, 0.f, 0.f};
    aH[t] = (f32x4){0.f, 0.f, 0.f, 0.f};
  }

  const short* az = zb + (size_t)arowc * 128 + g4 * 8;
  const short* ax = xb + (size_t)arowc * 128 + g4 * 8;
  const int laneOff = lane * 8;

#pragma unroll
  for (int ks = 0; ks < 4; ks++) {
    bf16x8 a = *(const bf16x8*)(az + ks * 32);
    int bo = ks * 512 + laneOff;
#pragma unroll
    for (int t = 0; t < 8; t++) {
      const short* bp = Fb + t * 2048 + bo;
      bf16x8 br = *(const bf16x8*)(bp);
      bf16x8 bz = *(const bf16x8*)(bp + 16384);
      bf16x8 bn = *(const bf16x8*)(bp + 32768);
      aR[t] = __builtin_amdgcn_mfma_f32_16x16x32_bf16(a, br, aR[t], 0, 0, 0);
      aZ[t] = __builtin_amdgcn_mfma_f32_16x16x32_bf16(a, bz, aZ[t], 0, 0, 0);
      aN[t] = __builtin_amdgcn_mfma_f32_16x16x32_bf16(a, bn, aN[t], 0, 0, 0);
    }
  }
#pragma unroll
  for (int ks = 0; ks < 4; ks++) {
    bf16x8 a = *(const bf16x8*)(ax + ks * 32);
    int bo = ks * 512 + laneOff;
#pragma unroll
    for (int t = 0; t < 8; t++) {
      const short* bp = Wb + t * 2048 + bo;
      bf16x8 br = *(const bf16x8*)(bp);
      bf16x8 bz = *(const bf16x8*)(bp + 16384);
      bf16x8 bn = *(const bf16x8*)(bp + 32768);
      aR[t] = __builtin_amdgcn_mfma_f32_16x16x32_bf16(a, br, aR[t], 0, 0, 0);
      aZ[t] = __builtin_amdgcn_mfma_f32_16x16x32_bf16(a, bz, aZ[t], 0, 0, 0);
      aH[t] = __builtin_amdgcn_mfma_f32_16x16x32_bf16(a, bn, aH[t], 0, 0, 0);
    }
  }

#pragma unroll
  for (int t = 0; t < 8; t++) {
    int col = t * 16 + m;
    float b_r = bih[col] + bhh[col];
    float b_z = bih[128 + col] + bhh[128 + col];
    float b_i = bih[256 + col];
    float b_h = bhh[256 + col];
#pragma unroll
    for (int r = 0; r < 4; r++) {
      int gr = rowBase + g4 * 4 + r;
      if (gr < N_NODES) {
        float rg = 1.f / (1.f + __expf(-(aR[t][r] + b_r)));
        float zg = 1.f / (1.f + __expf(-(aZ[t][r] + b_z)));
        float ng = tanhf(aN[t][r] + b_i + rg * (aH[t][r] + b_h));
        size_t o = (size_t)gr * 128 + col;
        float xo = x[o];
        float xn = (1.f - zg) * ng + zg * xo;
        x[o] = xn;
        xb[o] = (short)f2bf(xn);
      }
    }
  }
}

// ---------------------------------------------------------------------------
// BatchNorm (fp32 master x)
// ---------------------------------------------------------------------------
__global__ __launch_bounds__(256) void bn_stats(
    const float* __restrict__ x, float* __restrict__ sums)
{
  __shared__ float ls[256], lq[256];
  int tid  = threadIdx.x;
  int col  = tid & 127, half = tid >> 7;
  int r0   = blockIdx.x * 128;
  int rend = min(N_NODES, r0 + 128);
  float s = 0.f, q = 0.f;
  for (int r = r0 + half; r < rend; r += 2) {
    float v = x[(size_t)r * HDIM + col];
    s += v; q += v * v;
  }
  ls[tid] = s; lq[tid] = q;
  __syncthreads();
  if (tid < 128) {
    atomicAdd(&sums[col],       ls[tid] + ls[tid + 128]);
    atomicAdd(&sums[128 + col], lq[tid] + lq[tid + 128]);
  }
}

__global__ void bn_finalize(float* __restrict__ sums,
                            const float* __restrict__ gamma,
                            const float* __restrict__ beta)
{
  int j = threadIdx.x;
  float mean = sums[j] / (float)N_NODES;
  float var  = sums[128 + j] / (float)N_NODES - mean * mean;
  float inv  = rsqrtf(var + 1e-5f);
  sums[256 + j] = gamma[j] * inv;
  sums[384 + j] = beta[j] - mean * gamma[j] * inv;
}

__global__ __launch_bounds__(256) void bn_apply(
    float* __restrict__ x, const float* __restrict__ sums)
{
  int i = blockIdx.x * 256 + threadIdx.x;
  int j = i & 127;
  x[i] = x[i] * sums[256 + j] + sums[384 + j];
}

// ---------------------------------------------------------------------------
// Residual fold constants: E2 = embW @ mlpW  [128][40], c2 = mlpB + embB@mlpW
// ---------------------------------------------------------------------------
__global__ void prep_e2(const float* __restrict__ embW,
                        const float* __restrict__ embB,
                        const float* __restrict__ mlpW,
                        const float* __restrict__ mlpB,
                        float* __restrict__ e2, float* __restrict__ c2)
{
  int tid = threadIdx.x;
#pragma unroll
  for (int t = 0; t < 20; t++) {
    int idx = tid * 20 + t;
    int f = idx / 40, j = idx - f * 40;
    float s = 0.f;
    for (int k = 0; k < 128; k++)
      s = fmaf(embW[f * 128 + k], mlpW[k * 40 + j], s);
    e2[idx] = s;
  }
  if (tid < 40) {
    float s = mlpB[tid];
    for (int k = 0; k < 128; k++)
      s = fmaf(embB[k], mlpW[k * 40 + tid], s);
    c2[tid] = s;
  }
}

// ---------------------------------------------------------------------------
extern "C" void kernel_launch(void* const* d_in, const int* in_sizes, int n_in,
                              void* d_out, int out_size, void* d_ws, size_t ws_size,
                              hipStream_t stream)
{
  const float* h     = (const float*)d_in[0];
  const int*   ei    = (const int*)d_in[1];
  const float* ew    = (const float*)d_in[2];
  const float* embW  = (const float*)d_in[3];
  const float* embB  = (const float*)d_in[4];
  const float* convW = (const float*)d_in[5];   // [3][128][128]
  const float* Wih   = (const float*)d_in[6];   // [384][128]
  const float* Whh   = (const float*)d_in[7];   // [384][128]
  const float* bih   = (const float*)d_in[8];
  const float* bhh   = (const float*)d_in[9];
  const float* gamma = (const float*)d_in[10];
  const float* beta  = (const float*)d_in[11];
  const float* mlpW  = (const float*)d_in[12];
  const float* mlpB  = (const float*)d_in[13];
  float* out = (float*)d_out;

  float* ws = (float*)d_ws;
  const size_t NH = (size_t)N_NODES * HDIM;      // 12.8M
  float*    x      = ws;                          // [N][128] fp32 master
  unsigned* xbp    = (unsigned*)(ws + NH);        // [N][64] packed bf16
  unsigned* zbp    = xbp + NH / 2;                // [N][64] packed bf16
  int2*     epak   = (int2*)(zbp + NH / 2);       // [E] {src, w}
  int*      rowptr = (int*)(epak + N_EDGES);      // N+4
  int*      cnt    = rowptr + N_NODES + 4;        // N
  int*      deg    = cnt + N_NODES;               // N
  int*      blksum = deg + N_NODES;               // 64
  float*    Ffold  = (float*)(blksum + 64);       // [3][384][128] fp32
  short*    Fbp    = (short*)(Ffold + 3 * 384 * 128);  // frag-order bf16
  short*    Wbp    = Fbp + 3 * 384 * 128;         // frag-order bf16 of Whh
  float*    sums   = (float*)(Wbp + 384 * 128);
  float*    e2     = sums + 512;
  float*    c2     = e2 + 5120;
  // total ~131 MB

  dim3 blk(256);
  const int MB = (N_NODES + 63) / 64;
  const int EB = (N_EDGES + 255) / 256;
  const int RB = (384 * 128 + 255) / 256;
  const int SB = (N_NODES + 2047) / 2048;         // 49 scan blocks (<=64)

  // ---- constants ----
  prep_e2<<<1, 256, 0, stream>>>(embW, embB, mlpW, mlpB, e2, c2);
  for (int l = 0; l < 3; l++)
    gemm_k128<true, false><<<dim3(6, 1), blk, 0, stream>>>(
        Wih, convW + (size_t)l * HDIM * HDIM, nullptr,
        Ffold + (size_t)l * 384 * HDIM, 384, 128);
  for (int l = 0; l < 3; l++)
    repack_frag_b<<<RB, blk, 0, stream>>>(
        Ffold + (size_t)l * 384 * HDIM, Fbp + (size_t)l * 384 * HDIM);
  repack_frag_b<<<RB, blk, 0, stream>>>(Whh, Wbp);

  // ---- CSR build ----
  zero_i32<<<(2 * N_NODES + 255) / 256, blk, 0, stream>>>(cnt, 2 * N_NODES);
  csr_hist<<<EB, blk, 0, stream>>>(ei, deg);
  scan_blk<<<SB, blk, 0, stream>>>(deg, rowptr, blksum);
  scan_top<<<1, 64, 0, stream>>>(blksum, SB, rowptr);
  scan_add<<<(N_NODES + 255) / 256, blk, 0, stream>>>(rowptr, blksum);
  csr_fill<<<EB, blk, 0, stream>>>(ei, ew, rowptr, cnt, epak);

  // ---- embedding: x = h @ embW + embB ; bf16 mirror ----
  gemm_k128<false, false><<<dim3(MB, 1), blk, 0, stream>>>(h, embW, embB, x, N_NODES, 128);
  f32_to_bf16_pack<<<(int)(NH / 2 + 255) / 256, blk, 0, stream>>>(x, xbp, (int)(NH / 2));

  // ---- 3 GRU layers: pull-agg (bf16) + fused MFMA GRU ----
  for (int l = 0; l < 3; l++) {
    agg_pull<<<(N_NODES + 3) / 4, blk, 0, stream>>>(xbp, rowptr, epak, zbp);
    gru_fused<<<MB, blk, 0, stream>>>(
        (const short*)zbp, (short*)xbp, x,
        Fbp + (size_t)l * 384 * HDIM, Wbp, bih, bhh);
  }

  // ---- BatchNorm + residual-folded head ----
  zero_f32<<<2, blk, 0, stream>>>(sums, 512);
  bn_stats<<<(N_NODES + 127) / 128, blk, 0, stream>>>(x, sums);
  bn_finalize<<<1, 128, 0, stream>>>(sums, gamma, beta);
  bn_apply<<<(int)(NH / 256), blk, 0, stream>>>(x, sums);

  gemm_k128<false, false><<<dim3(MB, 1), blk, 0, stream>>>(x, mlpW, c2, out, N_NODES, 40);
  gemm_k128<false, true><<<dim3(MB, 1), blk, 0, stream>>>(h, e2, nullptr, out, N_NODES, 40);
}

// Round 7
// 1632.432 us; speedup vs baseline: 3.4896x; 1.0465x over previous
//
#include <hip/hip_runtime.h>
#include <math.h>

#define N_NODES 100000
#define N_EDGES 3200000
#define HDIM 128

typedef __attribute__((ext_vector_type(8))) short bf16x8;
typedef __attribute__((ext_vector_type(4))) float f32x4;

__device__ __forceinline__ unsigned short f2bf(float f) {
  union { float f; unsigned u; } v; v.f = f;
  unsigned r = v.u + 0x7fffu + ((v.u >> 16) & 1u);
  return (unsigned short)(r >> 16);
}
__device__ __forceinline__ float bflo(unsigned p) {
  union { unsigned u; float f; } v; v.u = p << 16; return v.f;
}
__device__ __forceinline__ float bfhi(unsigned p) {
  union { unsigned u; float f; } v; v.u = p & 0xffff0000u; return v.f;
}

// ---------------------------------------------------------------------------
__global__ __launch_bounds__(256) void zero_i32(int* __restrict__ p, int n) {
  int i = blockIdx.x * 256 + threadIdx.x;
  if (i < n) p[i] = 0;
}
__global__ __launch_bounds__(256) void zero_f32(float* __restrict__ p, int n) {
  int i = blockIdx.x * 256 + threadIdx.x;
  if (i < n) p[i] = 0.f;
}
// pack 2 consecutive floats -> 2 bf16 in one u32
__global__ __launch_bounds__(256) void f32_to_bf16_pack(
    const float* __restrict__ src, unsigned* __restrict__ dst, int n2) {
  int i = blockIdx.x * 256 + threadIdx.x;
  if (i >= n2) return;
  dst[i] = (unsigned)f2bf(src[2 * i]) | ((unsigned)f2bf(src[2 * i + 1]) << 16);
}

// ---------------------------------------------------------------------------
// Repack a [384][128] fp32 weight matrix (row-major [col][k]) into
// MFMA-B-fragment-ordered bf16 (lane*16B contiguous per fragment).
// ---------------------------------------------------------------------------
__global__ __launch_bounds__(256) void repack_frag_b(
    const float* __restrict__ src, short* __restrict__ dst)
{
  int o = blockIdx.x * 256 + threadIdx.x;      // 0 .. 384*128-1
  if (o >= 384 * 128) return;
  int j    = o & 7;
  int lane = (o >> 3) & 63;
  int ks   = (o >> 9) & 3;
  int t    = o >> 11;
  int m  = lane & 15;
  int g4 = lane >> 4;
  dst[o] = (short)f2bf(src[(t * 16 + m) * 128 + ks * 32 + g4 * 8 + j]);
}

// ---------------------------------------------------------------------------
// Tiled fp32 GEMM, K fixed at 128 (emb, head, weight folds).
// ---------------------------------------------------------------------------
template<bool BT, bool ACC>
__global__ __launch_bounds__(256) void gemm_k128(
    const float* __restrict__ A, const float* __restrict__ W,
    const float* __restrict__ bias, float* __restrict__ Y,
    int M, int OUT)
{
  __shared__ alignas(16) float lds_a[32 * 68];
  __shared__ alignas(16) float lds_b[32 * 132];
  const int tid = threadIdx.x;
  const int tx = tid & 15;
  const int ty = tid >> 4;
  const int rowBase = blockIdx.x * 64;
  const int colBase = blockIdx.y * 128;

  float acc[4][8];
#pragma unroll
  for (int r = 0; r < 4; r++)
#pragma unroll
    for (int c = 0; c < 8; c++) acc[r][c] = 0.f;

  for (int k0 = 0; k0 < 128; k0 += 32) {
#pragma unroll
    for (int i = 0; i < 2; i++) {
      int idx = tid + i * 256;
      int r   = idx >> 3;
      int kk  = (idx & 7) << 2;
      int gr  = rowBase + r;
      float4 v = make_float4(0.f, 0.f, 0.f, 0.f);
      if (gr < M) v = *(const float4*)(A + (size_t)gr * HDIM + k0 + kk);
      lds_a[(kk + 0) * 68 + r] = v.x;
      lds_a[(kk + 1) * 68 + r] = v.y;
      lds_a[(kk + 2) * 68 + r] = v.z;
      lds_a[(kk + 3) * 68 + r] = v.w;
    }
    if (!BT) {
#pragma unroll
      for (int i = 0; i < 4; i++) {
        int idx = tid + i * 256;
        int kk  = idx >> 5;
        int j   = (idx & 31) << 2;
        int gj  = colBase + j;
        float4 v = make_float4(0.f, 0.f, 0.f, 0.f);
        if (gj < OUT) v = *(const float4*)(W + (size_t)(k0 + kk) * OUT + gj);
        *((float4*)&lds_b[kk * 132 + j]) = v;
      }
    } else {
#pragma unroll
      for (int i = 0; i < 4; i++) {
        int idx = tid + i * 256;
        int j   = idx >> 3;
        int k4  = (idx & 7) << 2;
        int gj  = colBase + j;
        float4 v = make_float4(0.f, 0.f, 0.f, 0.f);
        if (gj < OUT) v = *(const float4*)(W + (size_t)gj * HDIM + k0 + k4);
        lds_b[(k4 + 0) * 132 + j] = v.x;
        lds_b[(k4 + 1) * 132 + j] = v.y;
        lds_b[(k4 + 2) * 132 + j] = v.z;
        lds_b[(k4 + 3) * 132 + j] = v.w;
      }
    }
    __syncthreads();
#pragma unroll 8
    for (int kk = 0; kk < 32; kk++) {
      float4 a4 = *(const float4*)&lds_a[kk * 68 + ty * 4];
      float4 b0 = *(const float4*)&lds_b[kk * 132 + tx * 8];
      float4 b1 = *(const float4*)&lds_b[kk * 132 + tx * 8 + 4];
      float av[4] = {a4.x, a4.y, a4.z, a4.w};
      float bv[8] = {b0.x, b0.y, b0.z, b0.w, b1.x, b1.y, b1.z, b1.w};
#pragma unroll
      for (int r = 0; r < 4; r++)
#pragma unroll
        for (int c = 0; c < 8; c++)
          acc[r][c] = fmaf(av[r], bv[c], acc[r][c]);
    }
    __syncthreads();
  }

  int col = colBase + tx * 8;
  if (col >= OUT) return;
  float bv[8];
#pragma unroll
  for (int c = 0; c < 8; c++) bv[c] = bias ? bias[col + c] : 0.f;
#pragma unroll
  for (int r = 0; r < 4; r++) {
    int gr = rowBase + ty * 4 + r;
    if (gr >= M) continue;
    float* yp = Y + (size_t)gr * OUT + col;
    float4 o0 = make_float4(acc[r][0] + bv[0], acc[r][1] + bv[1],
                            acc[r][2] + bv[2], acc[r][3] + bv[3]);
    float4 o1 = make_float4(acc[r][4] + bv[4], acc[r][5] + bv[5],
                            acc[r][6] + bv[6], acc[r][7] + bv[7]);
    if (ACC) {
      float4 y0 = *(float4*)yp;
      float4 y1 = *(float4*)(yp + 4);
      o0.x += y0.x; o0.y += y0.y; o0.z += y0.z; o0.w += y0.w;
      o1.x += y1.x; o1.y += y1.y; o1.z += y1.z; o1.w += y1.w;
    }
    *(float4*)yp       = o0;
    *(float4*)(yp + 4) = o1;
  }
}

// ---------------------------------------------------------------------------
// CSR build (by destination), edges packed as int2{src, w_bits}.
// ---------------------------------------------------------------------------
__global__ __launch_bounds__(256) void csr_hist(
    const int* __restrict__ ei, int* __restrict__ deg)
{
  int e = blockIdx.x * 256 + threadIdx.x;
  if (e < N_EDGES) atomicAdd(&deg[ei[N_EDGES + e]], 1);
}

// ---- hierarchical exclusive scan of deg[N] -> rowptr[N+1] ----
__global__ __launch_bounds__(256) void scan_blk(
    const int* __restrict__ deg, int* __restrict__ rowptr,
    int* __restrict__ blksum)
{
  __shared__ int lds[256];
  int tid  = threadIdx.x;
  int idx0 = blockIdx.x * 2048 + tid * 8;
  int v[8];
  int local = 0;
#pragma unroll
  for (int j = 0; j < 8; j++) {
    int i = idx0 + j;
    v[j] = (i < N_NODES) ? deg[i] : 0;
    local += v[j];
  }
  lds[tid] = local;
  __syncthreads();
  int inc = local;
  for (int off = 1; off < 256; off <<= 1) {
    int t = (tid >= off) ? lds[tid - off] : 0;
    __syncthreads();
    lds[tid] += t;
    __syncthreads();
  }
  int run = lds[tid] - inc;
#pragma unroll
  for (int j = 0; j < 8; j++) {
    int i = idx0 + j;
    if (i < N_NODES) rowptr[i] = run;
    run += v[j];
  }
  if (tid == 255) blksum[blockIdx.x] = lds[255];
}

__global__ void scan_top(int* __restrict__ blksum, int nblk,
                         int* __restrict__ rowptr)
{
  int tid = threadIdx.x;             // 64 threads
  int orig = (tid < nblk) ? blksum[tid] : 0;
  int v = orig;
  for (int off = 1; off < 64; off <<= 1) {
    int t = __shfl_up(v, off, 64);
    if (tid >= off) v += t;
  }
  if (tid < nblk) blksum[tid] = v - orig;
  if (tid == 63) rowptr[N_NODES] = v;
}

__global__ __launch_bounds__(256) void scan_add(
    int* __restrict__ rowptr, const int* __restrict__ blksum)
{
  int i = blockIdx.x * 256 + threadIdx.x;
  if (i < N_NODES) rowptr[i] += blksum[i >> 11];
}

__global__ __launch_bounds__(256) void csr_fill(
    const int* __restrict__ ei, const float* __restrict__ ew,
    const int* __restrict__ rowptr, int* __restrict__ cnt,
    int2* __restrict__ epak)
{
  int e = blockIdx.x * 256 + threadIdx.x;
  if (e >= N_EDGES) return;
  int d = ei[N_EDGES + e];
  int pos = rowptr[d] + atomicAdd(&cnt[d], 1);
  epak[pos] = make_int2(ei[e], __float_as_int(ew[e]));
}

// ---------------------------------------------------------------------------
// Pull aggregation on bf16 x: z[n] = sum w_e * x[src_e], fp32 accumulate,
// bf16 packed output. One wave/node, lane covers cols {2*lane, 2*lane+1}.
// ---------------------------------------------------------------------------
__global__ __launch_bounds__(256) void agg_pull(
    const unsigned* __restrict__ xbp, const int* __restrict__ rowptr,
    const int2* __restrict__ epak, unsigned* __restrict__ zbp)
{
  int node = blockIdx.x * 4 + (threadIdx.x >> 6);
  if (node >= N_NODES) return;
  int lane = threadIdx.x & 63;
  int s0 = rowptr[node], s1 = rowptr[node + 1];
  float v0 = 0.f, v1 = 0.f;
  int e = s0;
  for (; e + 3 < s1; e += 4) {
    int2 e0 = epak[e], e1 = epak[e + 1], e2 = epak[e + 2], e3 = epak[e + 3];
    unsigned p0 = xbp[(size_t)e0.x * 64 + lane];
    unsigned p1 = xbp[(size_t)e1.x * 64 + lane];
    unsigned p2 = xbp[(size_t)e2.x * 64 + lane];
    unsigned p3 = xbp[(size_t)e3.x * 64 + lane];
    float w0 = __int_as_float(e0.y), w1 = __int_as_float(e1.y);
    float w2 = __int_as_float(e2.y), w3 = __int_as_float(e3.y);
    v0 = fmaf(w0, bflo(p0), v0); v1 = fmaf(w0, bfhi(p0), v1);
    v0 = fmaf(w1, bflo(p1), v0); v1 = fmaf(w1, bfhi(p1), v1);
    v0 = fmaf(w2, bflo(p2), v0); v1 = fmaf(w2, bfhi(p2), v1);
    v0 = fmaf(w3, bflo(p3), v0); v1 = fmaf(w3, bfhi(p3), v1);
  }
  for (; e < s1; e++) {
    int2 ep = epak[e];
    unsigned p = xbp[(size_t)ep.x * 64 + lane];
    float w = __int_as_float(ep.y);
    v0 = fmaf(w, bflo(p), v0); v1 = fmaf(w, bfhi(p), v1);
  }
  zbp[(size_t)node * 64 + lane] =
      (unsigned)f2bf(v0) | ((unsigned)f2bf(v1) << 16);
}

// ---------------------------------------------------------------------------
// Fused GRU layer (bf16 MFMA), v2 partition: block = 64 rows; each of the
// 4 waves owns 2 of the 8 t-column-tiles (32 gate-cols x 3 gates) for ALL
// 64 rows. B-frag loads amortize over 4 row-tiles -> 4:1 MFMA:VMEM with
// 4-way independent MFMAs per load. Accums: 4rt x 2t x 4 sets = 128 VGPR.
// ---------------------------------------------------------------------------
__global__ __launch_bounds__(256) void gru_fused(
    const short* __restrict__ zb, short* __restrict__ xb,
    float* __restrict__ x,
    const short* __restrict__ Fb, const short* __restrict__ Wb,
    const float* __restrict__ bih, const float* __restrict__ bhh)
{
  const int wave = threadIdx.x >> 6, lane = threadIdx.x & 63;
  const int m  = lane & 15;
  const int g4 = lane >> 4;
  const int rowBase = blockIdx.x * 64;
  const int t0 = wave * 2;                 // this wave's t-pair (cols t0*16..)

  f32x4 aR[4][2], aZ[4][2], aN[4][2], aH[4][2];
#pragma unroll
  for (int rt = 0; rt < 4; rt++)
#pragma unroll
    for (int ti = 0; ti < 2; ti++) {
      aR[rt][ti] = (f32x4){0.f, 0.f, 0.f, 0.f};
      aZ[rt][ti] = (f32x4){0.f, 0.f, 0.f, 0.f};
      aN[rt][ti] = (f32x4){0.f, 0.f, 0.f, 0.f};
      aH[rt][ti] = (f32x4){0.f, 0.f, 0.f, 0.f};
    }

  size_t arowc[4];
#pragma unroll
  for (int rt = 0; rt < 4; rt++) {
    int arow = rowBase + rt * 16 + m;
    arowc[rt] = (size_t)(arow < N_NODES ? arow : N_NODES - 1) * 128 + g4 * 8;
  }

  // ---- phase 0: z @ F -> r,z,i_n ----
#pragma unroll
  for (int ks = 0; ks < 4; ks++) {
    bf16x8 a[4];
#pragma unroll
    for (int rt = 0; rt < 4; rt++)
      a[rt] = *(const bf16x8*)(zb + arowc[rt] + ks * 32);
    const int bo = ks * 512 + lane * 8;
#pragma unroll
    for (int ti = 0; ti < 2; ti++) {
      const short* bp = Fb + (t0 + ti) * 2048 + bo;
      bf16x8 br = *(const bf16x8*)(bp);
      bf16x8 bz = *(const bf16x8*)(bp + 16384);
      bf16x8 bn = *(const bf16x8*)(bp + 32768);
#pragma unroll
      for (int rt = 0; rt < 4; rt++) {
        aR[rt][ti] = __builtin_amdgcn_mfma_f32_16x16x32_bf16(a[rt], br, aR[rt][ti], 0, 0, 0);
        aZ[rt][ti] = __builtin_amdgcn_mfma_f32_16x16x32_bf16(a[rt], bz, aZ[rt][ti], 0, 0, 0);
        aN[rt][ti] = __builtin_amdgcn_mfma_f32_16x16x32_bf16(a[rt], bn, aN[rt][ti], 0, 0, 0);
      }
    }
  }
  // ---- phase 1: x @ Whh^T -> r,z,h_n ----
#pragma unroll
  for (int ks = 0; ks < 4; ks++) {
    bf16x8 a[4];
#pragma unroll
    for (int rt = 0; rt < 4; rt++)
      a[rt] = *(const bf16x8*)(xb + arowc[rt] + ks * 32);
    const int bo = ks * 512 + lane * 8;
#pragma unroll
    for (int ti = 0; ti < 2; ti++) {
      const short* bp = Wb + (t0 + ti) * 2048 + bo;
      bf16x8 br = *(const bf16x8*)(bp);
      bf16x8 bz = *(const bf16x8*)(bp + 16384);
      bf16x8 bn = *(const bf16x8*)(bp + 32768);
#pragma unroll
      for (int rt = 0; rt < 4; rt++) {
        aR[rt][ti] = __builtin_amdgcn_mfma_f32_16x16x32_bf16(a[rt], br, aR[rt][ti], 0, 0, 0);
        aZ[rt][ti] = __builtin_amdgcn_mfma_f32_16x16x32_bf16(a[rt], bz, aZ[rt][ti], 0, 0, 0);
        aH[rt][ti] = __builtin_amdgcn_mfma_f32_16x16x32_bf16(a[rt], bn, aH[rt][ti], 0, 0, 0);
      }
    }
  }

  // ---- epilogue: gates + state update (C/D: col=lane&15, row=g4*4+reg) ----
#pragma unroll
  for (int ti = 0; ti < 2; ti++) {
    int col = (t0 + ti) * 16 + m;
    float b_r = bih[col] + bhh[col];
    float b_z = bih[128 + col] + bhh[128 + col];
    float b_i = bih[256 + col];
    float b_h = bhh[256 + col];
#pragma unroll
    for (int rt = 0; rt < 4; rt++) {
#pragma unroll
      for (int r = 0; r < 4; r++) {
        int gr = rowBase + rt * 16 + g4 * 4 + r;
        if (gr < N_NODES) {
          float rg = 1.f / (1.f + __expf(-(aR[rt][ti][r] + b_r)));
          float zg = 1.f / (1.f + __expf(-(aZ[rt][ti][r] + b_z)));
          float ng = tanhf(aN[rt][ti][r] + b_i + rg * (aH[rt][ti][r] + b_h));
          size_t o = (size_t)gr * 128 + col;
          float xo = x[o];
          float xn = (1.f - zg) * ng + zg * xo;
          x[o] = xn;
          xb[o] = (short)f2bf(xn);
        }
      }
    }
  }
}

// ---------------------------------------------------------------------------
// BatchNorm (fp32 master x)
// ---------------------------------------------------------------------------
__global__ __launch_bounds__(256) void bn_stats(
    const float* __restrict__ x, float* __restrict__ sums)
{
  __shared__ float ls[256], lq[256];
  int tid  = threadIdx.x;
  int col  = tid & 127, half = tid >> 7;
  int r0   = blockIdx.x * 128;
  int rend = min(N_NODES, r0 + 128);
  float s = 0.f, q = 0.f;
  for (int r = r0 + half; r < rend; r += 2) {
    float v = x[(size_t)r * HDIM + col];
    s += v; q += v * v;
  }
  ls[tid] = s; lq[tid] = q;
  __syncthreads();
  if (tid < 128) {
    atomicAdd(&sums[col],       ls[tid] + ls[tid + 128]);
    atomicAdd(&sums[128 + col], lq[tid] + lq[tid + 128]);
  }
}

__global__ void bn_finalize(float* __restrict__ sums,
                            const float* __restrict__ gamma,
                            const float* __restrict__ beta)
{
  int j = threadIdx.x;
  float mean = sums[j] / (float)N_NODES;
  float var  = sums[128 + j] / (float)N_NODES - mean * mean;
  float inv  = rsqrtf(var + 1e-5f);
  sums[256 + j] = gamma[j] * inv;
  sums[384 + j] = beta[j] - mean * gamma[j] * inv;
}

__global__ __launch_bounds__(256) void bn_apply(
    float* __restrict__ x, const float* __restrict__ sums)
{
  int i = blockIdx.x * 256 + threadIdx.x;
  int j = i & 127;
  x[i] = x[i] * sums[256 + j] + sums[384 + j];
}

// ---------------------------------------------------------------------------
// Residual fold constants: E2 = embW @ mlpW  [128][40], c2 = mlpB + embB@mlpW
// ---------------------------------------------------------------------------
__global__ void prep_e2(const float* __restrict__ embW,
                        const float* __restrict__ embB,
                        const float* __restrict__ mlpW,
                        const float* __restrict__ mlpB,
                        float* __restrict__ e2, float* __restrict__ c2)
{
  int tid = threadIdx.x;
#pragma unroll
  for (int t = 0; t < 20; t++) {
    int idx = tid * 20 + t;
    int f = idx / 40, j = idx - f * 40;
    float s = 0.f;
    for (int k = 0; k < 128; k++)
      s = fmaf(embW[f * 128 + k], mlpW[k * 40 + j], s);
    e2[idx] = s;
  }
  if (tid < 40) {
    float s = mlpB[tid];
    for (int k = 0; k < 128; k++)
      s = fmaf(embB[k], mlpW[k * 40 + tid], s);
    c2[tid] = s;
  }
}

// ---------------------------------------------------------------------------
extern "C" void kernel_launch(void* const* d_in, const int* in_sizes, int n_in,
                              void* d_out, int out_size, void* d_ws, size_t ws_size,
                              hipStream_t stream)
{
  const float* h     = (const float*)d_in[0];
  const int*   ei    = (const int*)d_in[1];
  const float* ew    = (const float*)d_in[2];
  const float* embW  = (const float*)d_in[3];
  const float* embB  = (const float*)d_in[4];
  const float* convW = (const float*)d_in[5];   // [3][128][128]
  const float* Wih   = (const float*)d_in[6];   // [384][128]
  const float* Whh   = (const float*)d_in[7];   // [384][128]
  const float* bih   = (const float*)d_in[8];
  const float* bhh   = (const float*)d_in[9];
  const float* gamma = (const float*)d_in[10];
  const float* beta  = (const float*)d_in[11];
  const float* mlpW  = (const float*)d_in[12];
  const float* mlpB  = (const float*)d_in[13];
  float* out = (float*)d_out;

  float* ws = (float*)d_ws;
  const size_t NH = (size_t)N_NODES * HDIM;      // 12.8M
  float*    x      = ws;                          // [N][128] fp32 master
  unsigned* xbp    = (unsigned*)(ws + NH);        // [N][64] packed bf16
  unsigned* zbp    = xbp + NH / 2;                // [N][64] packed bf16
  int2*     epak   = (int2*)(zbp + NH / 2);       // [E] {src, w}
  int*      rowptr = (int*)(epak + N_EDGES);      // N+4
  int*      cnt    = rowptr + N_NODES + 4;        // N
  int*      deg    = cnt + N_NODES;               // N
  int*      blksum = deg + N_NODES;               // 64
  float*    Ffold  = (float*)(blksum + 64);       // [3][384][128] fp32
  short*    Fbp    = (short*)(Ffold + 3 * 384 * 128);  // frag-order bf16
  short*    Wbp    = Fbp + 3 * 384 * 128;         // frag-order bf16 of Whh
  float*    sums   = (float*)(Wbp + 384 * 128);
  float*    e2     = sums + 512;
  float*    c2     = e2 + 5120;
  // total ~131 MB

  dim3 blk(256);
  const int MB = (N_NODES + 63) / 64;
  const int EB = (N_EDGES + 255) / 256;
  const int RB = (384 * 128 + 255) / 256;
  const int SB = (N_NODES + 2047) / 2048;         // 49 scan blocks (<=64)

  // ---- constants ----
  prep_e2<<<1, 256, 0, stream>>>(embW, embB, mlpW, mlpB, e2, c2);
  for (int l = 0; l < 3; l++)
    gemm_k128<true, false><<<dim3(6, 1), blk, 0, stream>>>(
        Wih, convW + (size_t)l * HDIM * HDIM, nullptr,
        Ffold + (size_t)l * 384 * HDIM, 384, 128);
  for (int l = 0; l < 3; l++)
    repack_frag_b<<<RB, blk, 0, stream>>>(
        Ffold + (size_t)l * 384 * HDIM, Fbp + (size_t)l * 384 * HDIM);
  repack_frag_b<<<RB, blk, 0, stream>>>(Whh, Wbp);

  // ---- CSR build ----
  zero_i32<<<(2 * N_NODES + 255) / 256, blk, 0, stream>>>(cnt, 2 * N_NODES);
  csr_hist<<<EB, blk, 0, stream>>>(ei, deg);
  scan_blk<<<SB, blk, 0, stream>>>(deg, rowptr, blksum);
  scan_top<<<1, 64, 0, stream>>>(blksum, SB, rowptr);
  scan_add<<<(N_NODES + 255) / 256, blk, 0, stream>>>(rowptr, blksum);
  csr_fill<<<EB, blk, 0, stream>>>(ei, ew, rowptr, cnt, epak);

  // ---- embedding: x = h @ embW + embB ; bf16 mirror ----
  gemm_k128<false, false><<<dim3(MB, 1), blk, 0, stream>>>(h, embW, embB, x, N_NODES, 128);
  f32_to_bf16_pack<<<(int)(NH / 2 + 255) / 256, blk, 0, stream>>>(x, xbp, (int)(NH / 2));

  // ---- 3 GRU layers: pull-agg (bf16) + fused MFMA GRU ----
  for (int l = 0; l < 3; l++) {
    agg_pull<<<(N_NODES + 3) / 4, blk, 0, stream>>>(xbp, rowptr, epak, zbp);
    gru_fused<<<MB, blk, 0, stream>>>(
        (const short*)zbp, (short*)xbp, x,
        Fbp + (size_t)l * 384 * HDIM, Wbp, bih, bhh);
  }

  // ---- BatchNorm + residual-folded head ----
  zero_f32<<<2, blk, 0, stream>>>(sums, 512);
  bn_stats<<<(N_NODES + 127) / 128, blk, 0, stream>>>(x, sums);
  bn_finalize<<<1, 128, 0, stream>>>(sums, gamma, beta);
  bn_apply<<<(int)(NH / 256), blk, 0, stream>>>(x, sums);

  gemm_k128<false, false><<<dim3(MB, 1), blk, 0, stream>>>(x, mlpW, c2, out, N_NODES, 40);
  gemm_k128<false, true><<<dim3(MB, 1), blk, 0, stream>>>(h, e2, nullptr, out, N_NODES, 40);
}